// Round 1
// baseline (1002.357 us; speedup 1.0000x reference)
//
#include <hip/hip_runtime.h>
#include <hip/hip_bf16.h>

// GCN link predictor:
//   h = relu(gcnconv(x, W1, b1));  z = gcnconv(h, W2, b2);
//   out[e] = dot(z[eli0[e]], z[eli1[e]])
// gcnconv(x,W,b): h=x@W; deg=indeg(dst)+1; dinv=rsqrt(deg);
//   out[i] = dinv[i]*( sum_{e:dst=i} h[src]*dinv[src] + h[i]*dinv[i] ) + b
// We store g = h*dinv from the GEMM epilogue so aggregation is a plain gather-sum.

#define DH 128

// ---------------- CSR build ----------------

__global__ void count_kernel(const int* __restrict__ dst, int E, int* __restrict__ indeg) {
    int i = blockIdx.x * blockDim.x + threadIdx.x;
    if (i < E) atomicAdd(&indeg[dst[i]], 1);
}

__global__ __launch_bounds__(1024) void scan_kernel(
    const int* __restrict__ indeg, int* __restrict__ rowptr, int* __restrict__ cursor,
    float* __restrict__ dinv, int N) {
    __shared__ int sums[1024];
    int t = threadIdx.x;
    int chunk = (N + 1023) / 1024;
    int s = t * chunk;
    int e = min(N, s + chunk);
    int sum = 0;
    for (int i = s; i < e; i++) sum += indeg[i];
    sums[t] = sum;
    __syncthreads();
    // inclusive Hillis-Steele scan over 1024 partials
    for (int off = 1; off < 1024; off <<= 1) {
        int v = (t >= off) ? sums[t - off] : 0;
        __syncthreads();
        sums[t] += v;
        __syncthreads();
    }
    int run = (t == 0) ? 0 : sums[t - 1];
    for (int i = s; i < e; i++) {
        rowptr[i] = run;
        cursor[i] = run;
        int d = indeg[i];
        dinv[i] = 1.0f / sqrtf((float)(d + 1));
        run += d;
    }
    if (t == 1023) rowptr[N] = run;   // == E
}

__global__ void fill_kernel(const int* __restrict__ src, const int* __restrict__ dst, int E,
                            int* __restrict__ cursor, int* __restrict__ adj) {
    int i = blockIdx.x * blockDim.x + threadIdx.x;
    if (i < E) {
        int p = atomicAdd(&cursor[dst[i]], 1);
        adj[p] = src[i];
    }
}

// ---------------- GEMM: out[m][n] = (sum_k A[m][k]*B[k][n]) * dinv[m], N=128 ----------------

#define BM 128
#define BK 16

__global__ __launch_bounds__(256) void gemm_scale_kernel(
    const float* __restrict__ A, const float* __restrict__ B,
    const float* __restrict__ dinv, float* __restrict__ out,
    int M, int K) {
    __shared__ float Alds[BK][BM + 4];   // transposed: Alds[k][m], row stride 132 (528B, 16B-aligned)
    __shared__ float Blds[BK][DH];
    int t  = threadIdx.x;
    int tx = t % 16;       // column group (8 cols each)
    int ty = t / 16;       // row group (8 rows each)
    int m0 = blockIdx.x * BM;
    float acc[8][8];
#pragma unroll
    for (int i = 0; i < 8; i++)
#pragma unroll
        for (int j = 0; j < 8; j++) acc[i][j] = 0.f;

    for (int k0 = 0; k0 < K; k0 += BK) {
        // A tile: BM x BK = 2048 floats = 512 float4, 2 per thread; store transposed
#pragma unroll
        for (int l = 0; l < 2; l++) {
            int lin = t + l * 256;        // 0..511
            int row = lin >> 2;           // m within tile, 0..127
            int c4  = lin & 3;            // float4 along k
            int m = m0 + row;
            float4 v = make_float4(0.f, 0.f, 0.f, 0.f);
            if (m < M) v = *(const float4*)&A[(size_t)m * K + k0 + c4 * 4];
            Alds[c4 * 4 + 0][row] = v.x;
            Alds[c4 * 4 + 1][row] = v.y;
            Alds[c4 * 4 + 2][row] = v.z;
            Alds[c4 * 4 + 3][row] = v.w;
        }
        // B tile: BK x 128 = 2048 floats
#pragma unroll
        for (int l = 0; l < 2; l++) {
            int lin = t + l * 256;
            int row = lin >> 5;           // k 0..15
            int c4  = lin & 31;           // float4 along n
            *(float4*)&Blds[row][c4 * 4] = *(const float4*)&B[(size_t)(k0 + row) * DH + c4 * 4];
        }
        __syncthreads();
#pragma unroll
        for (int kk = 0; kk < BK; kk++) {
            float a[8], b[8];
            *(float4*)&a[0] = *(const float4*)&Alds[kk][ty * 8];
            *(float4*)&a[4] = *(const float4*)&Alds[kk][ty * 8 + 4];
            *(float4*)&b[0] = *(const float4*)&Blds[kk][tx * 8];
            *(float4*)&b[4] = *(const float4*)&Blds[kk][tx * 8 + 4];
#pragma unroll
            for (int i = 0; i < 8; i++)
#pragma unroll
                for (int j = 0; j < 8; j++)
                    acc[i][j] = fmaf(a[i], b[j], acc[i][j]);
        }
        __syncthreads();
    }
#pragma unroll
    for (int i = 0; i < 8; i++) {
        int m = m0 + ty * 8 + i;
        if (m < M) {
            float s = dinv[m];
            float4 v0 = make_float4(acc[i][0] * s, acc[i][1] * s, acc[i][2] * s, acc[i][3] * s);
            float4 v1 = make_float4(acc[i][4] * s, acc[i][5] * s, acc[i][6] * s, acc[i][7] * s);
            *(float4*)&out[(size_t)m * DH + tx * 8]     = v0;
            *(float4*)&out[(size_t)m * DH + tx * 8 + 4] = v1;
        }
    }
}

// ---------------- Aggregation: out[i] = dinv[i]*(g[i] + sum_j g[adj]) + b, optional relu ------

__global__ __launch_bounds__(128) void agg_kernel(
    const float* __restrict__ g, const int* __restrict__ rowptr,
    const int* __restrict__ adj, const float* __restrict__ dinv,
    const float* __restrict__ bias, float* __restrict__ out,
    int N, int do_relu) {
    int i = blockIdx.x;
    int c = threadIdx.x;      // 0..127
    int r0 = rowptr[i], r1 = rowptr[i + 1];
    float acc = g[(size_t)i * DH + c];   // self-loop term (g = h*dinv, self adds g[i]*dinv[i] later)
    __shared__ int sj[128];
    for (int base = r0; base < r1; base += 128) {
        int cnt = min(128, r1 - base);
        if (c < cnt) sj[c] = adj[base + c];
        __syncthreads();
        for (int r = 0; r < cnt; r++)
            acc += g[(size_t)sj[r] * DH + c];
        __syncthreads();
    }
    float v = dinv[i] * acc + bias[c];
    if (do_relu) v = fmaxf(v, 0.f);
    out[(size_t)i * DH + c] = v;
}

// ---------------- Decode: out[e] = dot(z[a], z[b]) over 128 ----------------

__global__ __launch_bounds__(256) void decode_kernel(
    const float* __restrict__ z, const int* __restrict__ ea, const int* __restrict__ eb,
    float* __restrict__ out, int EL) {
    int w    = (blockIdx.x * blockDim.x + threadIdx.x) >> 6;   // wave id = edge id
    int lane = threadIdx.x & 63;
    if (w >= EL) return;
    int a = ea[w], b = eb[w];
    const float* za = &z[(size_t)a * DH];
    const float* zb = &z[(size_t)b * DH];
    float acc = za[lane] * zb[lane] + za[lane + 64] * zb[lane + 64];
#pragma unroll
    for (int off = 32; off > 0; off >>= 1)
        acc += __shfl_down(acc, off, 64);
    if (lane == 0) out[w] = acc;
}

// ---------------- Launch ----------------

extern "C" void kernel_launch(void* const* d_in, const int* in_sizes, int n_in,
                              void* d_out, int out_size, void* d_ws, size_t ws_size,
                              hipStream_t stream) {
    const float* x   = (const float*)d_in[0];
    const int*   ei  = (const int*)d_in[1];
    const int*   eli = (const int*)d_in[2];
    const float* W1  = (const float*)d_in[3];
    const float* b1  = (const float*)d_in[4];
    const float* W2  = (const float*)d_in[5];
    const float* b2  = (const float*)d_in[6];
    float* out = (float*)d_out;

    int DHv = in_sizes[4];                 // 128
    int DIN = in_sizes[3] / DHv;           // 256
    int N   = in_sizes[0] / DIN;           // 100000
    int E   = in_sizes[1] / 2;             // 1600000
    int EL  = in_sizes[2] / 2;             // 200000
    const int* src = ei;
    const int* dst = ei + E;
    const int* ea = eli;
    const int* eb = eli + EL;

    // workspace carve-up (256B aligned)
    char* ws = (char*)d_ws;
    size_t off = 0;
    auto alloc = [&](size_t bytes) {
        void* p = ws + off;
        off += (bytes + 255) & ~(size_t)255;
        return p;
    };
    int*   indeg  = (int*)alloc((size_t)N * 4);
    int*   cursor = (int*)alloc((size_t)N * 4);
    int*   rowptr = (int*)alloc((size_t)(N + 1) * 4);
    int*   adj    = (int*)alloc((size_t)E * 4);
    float* dinv   = (float*)alloc((size_t)N * 4);
    float* buf1   = (float*)alloc((size_t)N * DH * 4);   // g1, then g2
    float* buf2   = (float*)alloc((size_t)N * DH * 4);   // hrelu, then z

    hipMemsetAsync(indeg, 0, (size_t)N * 4, stream);
    count_kernel<<<(E + 255) / 256, 256, 0, stream>>>(dst, E, indeg);
    scan_kernel<<<1, 1024, 0, stream>>>(indeg, rowptr, cursor, dinv, N);
    fill_kernel<<<(E + 255) / 256, 256, 0, stream>>>(src, dst, E, cursor, adj);

    int gemm_blocks = (N + BM - 1) / BM;
    // conv1: g1 = (x @ W1) * dinv
    gemm_scale_kernel<<<gemm_blocks, 256, 0, stream>>>(x, W1, dinv, buf1, N, DIN);
    // hrelu = relu(dinv*(g1_self + sum g1[adj]) + b1)
    agg_kernel<<<N, 128, 0, stream>>>(buf1, rowptr, adj, dinv, b1, buf2, N, 1);
    // conv2: g2 = (hrelu @ W2) * dinv
    gemm_scale_kernel<<<gemm_blocks, 256, 0, stream>>>(buf2, W2, dinv, buf1, N, DHv);
    // z = dinv*(g2_self + sum g2[adj]) + b2
    agg_kernel<<<N, 128, 0, stream>>>(buf1, rowptr, adj, dinv, b2, buf2, N, 0);
    // logits
    decode_kernel<<<(EL * 64 + 255) / 256, 256, 0, stream>>>(buf2, ea, eb, out, EL);
}

// Round 2
// 746.339 us; speedup vs baseline: 1.3430x; 1.3430x over previous
//
#include <hip/hip_runtime.h>
#include <hip/hip_bf16.h>

// GCN link predictor:
//   h = relu(gcnconv(x, W1, b1));  z = gcnconv(h, W2, b2);
//   out[e] = dot(z[eli0[e]], z[eli1[e]])
// gcnconv(x,W,b): h=x@W; deg=indeg(dst)+1; dinv=rsqrt(deg);
//   out[i] = dinv[i]*( sum_{e:dst=i} h[src]*dinv[src] + h[i]*dinv[i] ) + b
// We store g = h*dinv from the GEMM epilogue so aggregation is a plain gather-sum.

#define DH 128

// ---------------- CSR build ----------------

__global__ void count_kernel(const int* __restrict__ dst, int E, int* __restrict__ indeg) {
    int i = blockIdx.x * blockDim.x + threadIdx.x;
    if (i < E) atomicAdd(&indeg[dst[i]], 1);
}

// 3-phase parallel exclusive scan of indeg -> rowptr (+cursor, dinv).
// Phase 1: each 256-thread block sums a 1024-element chunk (int4 coalesced).
#define SCAN_CHUNK 1024

__global__ __launch_bounds__(256) void scan_part_kernel(
    const int* __restrict__ indeg, int* __restrict__ blocksum, int N) {
    __shared__ int red[256];
    int t = threadIdx.x;
    int base = blockIdx.x * SCAN_CHUNK + t * 4;
    int s = 0;
    if (base + 3 < N) {
        int4 v = *(const int4*)&indeg[base];
        s = v.x + v.y + v.z + v.w;
    } else {
#pragma unroll
        for (int i = 0; i < 4; i++) if (base + i < N) s += indeg[base + i];
    }
    red[t] = s;
    __syncthreads();
#pragma unroll
    for (int off = 128; off > 0; off >>= 1) {
        if (t < off) red[t] += red[t + off];
        __syncthreads();
    }
    if (t == 0) blocksum[blockIdx.x] = red[0];
}

// Phase 2: exclusive scan of B (<=1024) block sums, single block.
__global__ __launch_bounds__(1024) void scan_top_kernel(int* __restrict__ blocksum, int B) {
    __shared__ int s[1024];
    int t = threadIdx.x;
    int v = (t < B) ? blocksum[t] : 0;
    s[t] = v;
    __syncthreads();
    for (int off = 1; off < 1024; off <<= 1) {
        int u = (t >= off) ? s[t - off] : 0;
        __syncthreads();
        s[t] += u;
        __syncthreads();
    }
    if (t < B) blocksum[t] = s[t] - v;   // exclusive
}

// Phase 3: re-read chunk, intra-block scan, write rowptr/cursor/dinv.
__global__ __launch_bounds__(256) void scan_fill_kernel(
    const int* __restrict__ indeg, const int* __restrict__ blocksum,
    int* __restrict__ rowptr, int* __restrict__ cursor, float* __restrict__ dinv, int N) {
    __shared__ int tsum[256];
    int t = threadIdx.x;
    int base = blockIdx.x * SCAN_CHUNK + t * 4;
    int d[4];
    int s = 0;
#pragma unroll
    for (int i = 0; i < 4; i++) {
        d[i] = (base + i < N) ? indeg[base + i] : 0;
        s += d[i];
    }
    tsum[t] = s;
    __syncthreads();
    for (int off = 1; off < 256; off <<= 1) {
        int u = (t >= off) ? tsum[t - off] : 0;
        __syncthreads();
        tsum[t] += u;
        __syncthreads();
    }
    int run = blocksum[blockIdx.x] + ((t == 0) ? 0 : tsum[t - 1]);
#pragma unroll
    for (int i = 0; i < 4; i++) {
        int idx = base + i;
        if (idx < N) {
            rowptr[idx] = run;
            cursor[idx] = run;
            dinv[idx] = 1.0f / sqrtf((float)(d[i] + 1));
            run += d[i];
        }
    }
    if (base <= N - 1 && N - 1 < base + 4) rowptr[N] = run;   // total == E
}

__global__ void fill_kernel(const int* __restrict__ src, const int* __restrict__ dst, int E,
                            int* __restrict__ cursor, int* __restrict__ adj) {
    int i = blockIdx.x * blockDim.x + threadIdx.x;
    if (i < E) {
        int p = atomicAdd(&cursor[dst[i]], 1);
        adj[p] = src[i];
    }
}

// ---------------- GEMM: out[m][n] = (sum_k A[m][k]*B[k][n]) * dinv[m], N=128 ----------------

#define BM 128
#define BK 16

__global__ __launch_bounds__(256) void gemm_scale_kernel(
    const float* __restrict__ A, const float* __restrict__ B,
    const float* __restrict__ dinv, float* __restrict__ out,
    int M, int K) {
    __shared__ float Alds[BK][BM + 4];   // transposed: Alds[k][m]
    __shared__ float Blds[BK][DH];
    int t  = threadIdx.x;
    int tx = t % 16;       // column group (8 cols each)
    int ty = t / 16;       // row group (8 rows each)
    int m0 = blockIdx.x * BM;
    float acc[8][8];
#pragma unroll
    for (int i = 0; i < 8; i++)
#pragma unroll
        for (int j = 0; j < 8; j++) acc[i][j] = 0.f;

    for (int k0 = 0; k0 < K; k0 += BK) {
#pragma unroll
        for (int l = 0; l < 2; l++) {
            int lin = t + l * 256;        // 0..511
            int row = lin >> 2;           // m within tile, 0..127
            int c4  = lin & 3;            // float4 along k
            int m = m0 + row;
            float4 v = make_float4(0.f, 0.f, 0.f, 0.f);
            if (m < M) v = *(const float4*)&A[(size_t)m * K + k0 + c4 * 4];
            Alds[c4 * 4 + 0][row] = v.x;
            Alds[c4 * 4 + 1][row] = v.y;
            Alds[c4 * 4 + 2][row] = v.z;
            Alds[c4 * 4 + 3][row] = v.w;
        }
#pragma unroll
        for (int l = 0; l < 2; l++) {
            int lin = t + l * 256;
            int row = lin >> 5;           // k 0..15
            int c4  = lin & 31;           // float4 along n
            *(float4*)&Blds[row][c4 * 4] = *(const float4*)&B[(size_t)(k0 + row) * DH + c4 * 4];
        }
        __syncthreads();
#pragma unroll
        for (int kk = 0; kk < BK; kk++) {
            float a[8], b[8];
            *(float4*)&a[0] = *(const float4*)&Alds[kk][ty * 8];
            *(float4*)&a[4] = *(const float4*)&Alds[kk][ty * 8 + 4];
            *(float4*)&b[0] = *(const float4*)&Blds[kk][tx * 8];
            *(float4*)&b[4] = *(const float4*)&Blds[kk][tx * 8 + 4];
#pragma unroll
            for (int i = 0; i < 8; i++)
#pragma unroll
                for (int j = 0; j < 8; j++)
                    acc[i][j] = fmaf(a[i], b[j], acc[i][j]);
        }
        __syncthreads();
    }
#pragma unroll
    for (int i = 0; i < 8; i++) {
        int m = m0 + ty * 8 + i;
        if (m < M) {
            float s = dinv[m];
            float4 v0 = make_float4(acc[i][0] * s, acc[i][1] * s, acc[i][2] * s, acc[i][3] * s);
            float4 v1 = make_float4(acc[i][4] * s, acc[i][5] * s, acc[i][6] * s, acc[i][7] * s);
            *(float4*)&out[(size_t)m * DH + tx * 8]     = v0;
            *(float4*)&out[(size_t)m * DH + tx * 8 + 4] = v1;
        }
    }
}

// ---------------- Aggregation: out[i] = dinv[i]*(g[i] + sum_j g[adj]) + b, optional relu ------

__global__ __launch_bounds__(128) void agg_kernel(
    const float* __restrict__ g, const int* __restrict__ rowptr,
    const int* __restrict__ adj, const float* __restrict__ dinv,
    const float* __restrict__ bias, float* __restrict__ out,
    int N, int do_relu) {
    int i = blockIdx.x;
    int c = threadIdx.x;      // 0..127
    int r0 = rowptr[i], r1 = rowptr[i + 1];
    float acc = g[(size_t)i * DH + c];   // self-loop term
    __shared__ int sj[128];
    for (int base = r0; base < r1; base += 128) {
        int cnt = min(128, r1 - base);
        if (c < cnt) sj[c] = adj[base + c];
        __syncthreads();
        for (int r = 0; r < cnt; r++)
            acc += g[(size_t)sj[r] * DH + c];
        __syncthreads();
    }
    float v = dinv[i] * acc + bias[c];
    if (do_relu) v = fmaxf(v, 0.f);
    out[(size_t)i * DH + c] = v;
}

// ---------------- Decode: out[e] = dot(z[a], z[b]) over 128 ----------------

__global__ __launch_bounds__(256) void decode_kernel(
    const float* __restrict__ z, const int* __restrict__ ea, const int* __restrict__ eb,
    float* __restrict__ out, int EL) {
    int w    = (blockIdx.x * blockDim.x + threadIdx.x) >> 6;   // wave id = edge id
    int lane = threadIdx.x & 63;
    if (w >= EL) return;
    int a = ea[w], b = eb[w];
    const float* za = &z[(size_t)a * DH];
    const float* zb = &z[(size_t)b * DH];
    float acc = za[lane] * zb[lane] + za[lane + 64] * zb[lane + 64];
#pragma unroll
    for (int off = 32; off > 0; off >>= 1)
        acc += __shfl_down(acc, off, 64);
    if (lane == 0) out[w] = acc;
}

// ---------------- Launch ----------------

extern "C" void kernel_launch(void* const* d_in, const int* in_sizes, int n_in,
                              void* d_out, int out_size, void* d_ws, size_t ws_size,
                              hipStream_t stream) {
    const float* x   = (const float*)d_in[0];
    const int*   ei  = (const int*)d_in[1];
    const int*   eli = (const int*)d_in[2];
    const float* W1  = (const float*)d_in[3];
    const float* b1  = (const float*)d_in[4];
    const float* W2  = (const float*)d_in[5];
    const float* b2  = (const float*)d_in[6];
    float* out = (float*)d_out;

    int DHv = in_sizes[4];                 // 128
    int DIN = in_sizes[3] / DHv;           // 256
    int N   = in_sizes[0] / DIN;           // 100000
    int E   = in_sizes[1] / 2;             // 1600000
    int EL  = in_sizes[2] / 2;             // 200000
    const int* src = ei;
    const int* dst = ei + E;
    const int* ea = eli;
    const int* eb = eli + EL;

    // workspace carve-up (256B aligned)
    char* ws = (char*)d_ws;
    size_t off = 0;
    auto alloc = [&](size_t bytes) {
        void* p = ws + off;
        off += (bytes + 255) & ~(size_t)255;
        return p;
    };
    int scan_blocks = (N + SCAN_CHUNK - 1) / SCAN_CHUNK;   // 98
    int*   indeg    = (int*)alloc((size_t)N * 4);
    int*   cursor   = (int*)alloc((size_t)N * 4);
    int*   rowptr   = (int*)alloc((size_t)(N + 1) * 4);
    int*   adj      = (int*)alloc((size_t)E * 4);
    float* dinv     = (float*)alloc((size_t)N * 4);
    int*   blocksum = (int*)alloc((size_t)scan_blocks * 4);
    float* buf1     = (float*)alloc((size_t)N * DH * 4);   // g1, then g2
    float* buf2     = (float*)alloc((size_t)N * DH * 4);   // hrelu, then z

    hipMemsetAsync(indeg, 0, (size_t)N * 4, stream);
    count_kernel<<<(E + 255) / 256, 256, 0, stream>>>(dst, E, indeg);
    scan_part_kernel<<<scan_blocks, 256, 0, stream>>>(indeg, blocksum, N);
    scan_top_kernel<<<1, 1024, 0, stream>>>(blocksum, scan_blocks);
    scan_fill_kernel<<<scan_blocks, 256, 0, stream>>>(indeg, blocksum, rowptr, cursor, dinv, N);
    fill_kernel<<<(E + 255) / 256, 256, 0, stream>>>(src, dst, E, cursor, adj);

    int gemm_blocks = (N + BM - 1) / BM;
    // conv1: g1 = (x @ W1) * dinv
    gemm_scale_kernel<<<gemm_blocks, 256, 0, stream>>>(x, W1, dinv, buf1, N, DIN);
    // hrelu = relu(dinv*(g1_self + sum g1[adj]) + b1)
    agg_kernel<<<N, 128, 0, stream>>>(buf1, rowptr, adj, dinv, b1, buf2, N, 1);
    // conv2: g2 = (hrelu @ W2) * dinv
    gemm_scale_kernel<<<gemm_blocks, 256, 0, stream>>>(buf2, W2, dinv, buf1, N, DHv);
    // z = dinv*(g2_self + sum g2[adj]) + b2
    agg_kernel<<<N, 128, 0, stream>>>(buf1, rowptr, adj, dinv, b2, buf2, N, 0);
    // logits
    decode_kernel<<<(EL * 64 + 255) / 256, 256, 0, stream>>>(buf2, ea, eb, out, EL);
}

// Round 3
// 617.694 us; speedup vs baseline: 1.6227x; 1.2083x over previous
//
#include <hip/hip_runtime.h>
#include <hip/hip_bf16.h>

// GCN link predictor:
//   h = relu(gcnconv(x, W1, b1));  z = gcnconv(h, W2, b2);
//   out[e] = dot(z[eli0[e]], z[eli1[e]])
// gcnconv(x,W,b): h=x@W; deg=indeg(dst)+1; dinv=rsqrt(deg);
//   out[i] = dinv[i]*( sum_{e:dst=i} h[src]*dinv[src] + h[i]*dinv[i] ) + b
// g = h*dinv is produced by the GEMM epilogue so aggregation is a plain gather-sum.
//
// CSR build is bucket-partitioned to avoid random 4B scatter (R1: fill_kernel
// wrote 105 MB for a 6.4 MB adj array via partial-line writebacks):
//   bucket = dst>>8 (256 nodes/bucket). Stage A appends packed edges into
//   per-bucket regions (runs -> full cache lines). Stage B: one block per
//   bucket builds rowptr/deg/dinv via LDS scan and scatters adj inside a
//   16 KB XCD-local region with LDS cursors. No N-wide global atomics left.

#define DH 128
#define BUCKET_BITS 8
#define CAP 5120            // per-bucket edge capacity; mean 4096, sigma ~64 -> 16 sigma slack
#define EPB 4096            // edges per block in stage A

// ---------------- CSR build ----------------

__global__ __launch_bounds__(256) void init_cursor_kernel(int* __restrict__ cursor) {
    int i = blockIdx.x * 256 + threadIdx.x;    // 512 total
    cursor[i] = i * CAP;
}

// Stage A: partition edges into buckets by dst>>8; packed = src | (dst&255)<<17
// (valid for N <= 131072; here N = 100000).
__global__ __launch_bounds__(256) void bucket_scatter_kernel(
    const int* __restrict__ src, const int* __restrict__ dst, int E,
    int* __restrict__ cursor, int* __restrict__ pairs) {
    __shared__ int hist[512];
    __shared__ int base[512];
    int t = threadIdx.x;
    int e0 = blockIdx.x * EPB;
    hist[t] = 0; hist[t + 256] = 0;
    __syncthreads();
#pragma unroll
    for (int r = 0; r < EPB / 256; r++) {
        int i = e0 + r * 256 + t;
        if (i < E) atomicAdd(&hist[dst[i] >> BUCKET_BITS], 1);
    }
    __syncthreads();
#pragma unroll
    for (int b = t; b < 512; b += 256) {
        int h = hist[b];
        base[b] = h ? atomicAdd(&cursor[b], h) : 0;
    }
    __syncthreads();
    hist[t] = 0; hist[t + 256] = 0;
    __syncthreads();
#pragma unroll
    for (int r = 0; r < EPB / 256; r++) {
        int i = e0 + r * 256 + t;
        if (i < E) {
            int d = dst[i];
            int b = d >> BUCKET_BITS;
            int rk = atomicAdd(&hist[b], 1);
            pairs[base[b] + rk] = src[i] | ((d & 255) << 17);
        }
    }
}

// Stage B: per-bucket CSR finalize. rowptr/deg/dinv via LDS count+scan,
// adj scatter via LDS cursors into this bucket's private region.
__global__ __launch_bounds__(256) void bucket_build_kernel(
    const int* __restrict__ pairs, const int* __restrict__ cursor,
    int* __restrict__ rowptr, int* __restrict__ deg, float* __restrict__ dinv,
    int* __restrict__ adj, int N) {
    __shared__ int cnt[256];
    __shared__ int sc[256];
    __shared__ int basep[256];
    int b = blockIdx.x;
    int t = threadIdx.x;
    int nb0 = b << BUCKET_BITS;
    int p0 = b * CAP;
    int p1 = cursor[b];               // end of this bucket's pairs
    cnt[t] = 0;
    __syncthreads();
    for (int i = p0 + t; i < p1; i += 256)
        atomicAdd(&cnt[pairs[i] >> 17], 1);
    __syncthreads();
    int c = cnt[t];
    sc[t] = c;
    __syncthreads();
    for (int off = 1; off < 256; off <<= 1) {
        int u = (t >= off) ? sc[t - off] : 0;
        __syncthreads();
        sc[t] += u;
        __syncthreads();
    }
    int ex = sc[t] - c;               // exclusive scan within bucket
    int node = nb0 + t;
    if (node < N) {
        rowptr[node] = p0 + ex;
        deg[node]    = c;
        dinv[node]   = rsqrtf((float)(c + 1));
    }
    basep[t] = p0 + ex;
    cnt[t] = 0;
    __syncthreads();
    for (int i = p0 + t; i < p1; i += 256) {
        int v = pairs[i];
        int li = v >> 17;
        int rk = atomicAdd(&cnt[li], 1);
        adj[basep[li] + rk] = v & 0x1FFFF;
    }
}

// ---------------- GEMM: out[m][n] = (sum_k A[m][k]*B[k][n]) * dinv[m], N=128 ----------------

#define BM 128
#define BK 16

__global__ __launch_bounds__(256) void gemm_scale_kernel(
    const float* __restrict__ A, const float* __restrict__ B,
    const float* __restrict__ dinv, float* __restrict__ out,
    int M, int K) {
    __shared__ float Alds[BK][BM + 4];   // transposed: Alds[k][m]
    __shared__ float Blds[BK][DH];
    int t  = threadIdx.x;
    int tx = t % 16;       // column group (8 cols each)
    int ty = t / 16;       // row group (8 rows each)
    int m0 = blockIdx.x * BM;
    float acc[8][8];
#pragma unroll
    for (int i = 0; i < 8; i++)
#pragma unroll
        for (int j = 0; j < 8; j++) acc[i][j] = 0.f;

    for (int k0 = 0; k0 < K; k0 += BK) {
#pragma unroll
        for (int l = 0; l < 2; l++) {
            int lin = t + l * 256;        // 0..511
            int row = lin >> 2;           // m within tile, 0..127
            int c4  = lin & 3;            // float4 along k
            int m = m0 + row;
            float4 v = make_float4(0.f, 0.f, 0.f, 0.f);
            if (m < M) v = *(const float4*)&A[(size_t)m * K + k0 + c4 * 4];
            Alds[c4 * 4 + 0][row] = v.x;
            Alds[c4 * 4 + 1][row] = v.y;
            Alds[c4 * 4 + 2][row] = v.z;
            Alds[c4 * 4 + 3][row] = v.w;
        }
#pragma unroll
        for (int l = 0; l < 2; l++) {
            int lin = t + l * 256;
            int row = lin >> 5;           // k 0..15
            int c4  = lin & 31;           // float4 along n
            *(float4*)&Blds[row][c4 * 4] = *(const float4*)&B[(size_t)(k0 + row) * DH + c4 * 4];
        }
        __syncthreads();
#pragma unroll
        for (int kk = 0; kk < BK; kk++) {
            float a[8], bb[8];
            *(float4*)&a[0]  = *(const float4*)&Alds[kk][ty * 8];
            *(float4*)&a[4]  = *(const float4*)&Alds[kk][ty * 8 + 4];
            *(float4*)&bb[0] = *(const float4*)&Blds[kk][tx * 8];
            *(float4*)&bb[4] = *(const float4*)&Blds[kk][tx * 8 + 4];
#pragma unroll
            for (int i = 0; i < 8; i++)
#pragma unroll
                for (int j = 0; j < 8; j++)
                    acc[i][j] = fmaf(a[i], bb[j], acc[i][j]);
        }
        __syncthreads();
    }
#pragma unroll
    for (int i = 0; i < 8; i++) {
        int m = m0 + ty * 8 + i;
        if (m < M) {
            float s = dinv[m];
            float4 v0 = make_float4(acc[i][0] * s, acc[i][1] * s, acc[i][2] * s, acc[i][3] * s);
            float4 v1 = make_float4(acc[i][4] * s, acc[i][5] * s, acc[i][6] * s, acc[i][7] * s);
            *(float4*)&out[(size_t)m * DH + tx * 8]     = v0;
            *(float4*)&out[(size_t)m * DH + tx * 8 + 4] = v1;
        }
    }
}

// ---------------- Aggregation: out[i] = dinv[i]*(g[i] + sum_j g[adj]) + b, optional relu ------

__global__ __launch_bounds__(128) void agg_kernel(
    const float* __restrict__ g, const int* __restrict__ rowptr,
    const int* __restrict__ deg, const int* __restrict__ adj,
    const float* __restrict__ dinv, const float* __restrict__ bias,
    float* __restrict__ out, int N, int do_relu) {
    int i = blockIdx.x;
    int c = threadIdx.x;      // 0..127
    int r0 = rowptr[i], r1 = r0 + deg[i];
    float acc = g[(size_t)i * DH + c];   // self-loop term
    __shared__ int sj[128];
    for (int base = r0; base < r1; base += 128) {
        int cnt = min(128, r1 - base);
        if (c < cnt) sj[c] = adj[base + c];
        __syncthreads();
        for (int r = 0; r < cnt; r++)
            acc += g[(size_t)sj[r] * DH + c];
        __syncthreads();
    }
    float v = dinv[i] * acc + bias[c];
    if (do_relu) v = fmaxf(v, 0.f);
    out[(size_t)i * DH + c] = v;
}

// ---------------- Decode: out[e] = dot(z[a], z[b]) over 128 ----------------

__global__ __launch_bounds__(256) void decode_kernel(
    const float* __restrict__ z, const int* __restrict__ ea, const int* __restrict__ eb,
    float* __restrict__ out, int EL) {
    int w    = (blockIdx.x * blockDim.x + threadIdx.x) >> 6;   // wave id = edge id
    int lane = threadIdx.x & 63;
    if (w >= EL) return;
    int a = ea[w], b = eb[w];
    const float* za = &z[(size_t)a * DH];
    const float* zb = &z[(size_t)b * DH];
    float acc = za[lane] * zb[lane] + za[lane + 64] * zb[lane + 64];
#pragma unroll
    for (int off = 32; off > 0; off >>= 1)
        acc += __shfl_down(acc, off, 64);
    if (lane == 0) out[w] = acc;
}

// ---------------- Launch ----------------

extern "C" void kernel_launch(void* const* d_in, const int* in_sizes, int n_in,
                              void* d_out, int out_size, void* d_ws, size_t ws_size,
                              hipStream_t stream) {
    const float* x   = (const float*)d_in[0];
    const int*   ei  = (const int*)d_in[1];
    const int*   eli = (const int*)d_in[2];
    const float* W1  = (const float*)d_in[3];
    const float* b1  = (const float*)d_in[4];
    const float* W2  = (const float*)d_in[5];
    const float* b2  = (const float*)d_in[6];
    float* out = (float*)d_out;

    int DHv = in_sizes[4];                 // 128
    int DIN = in_sizes[3] / DHv;           // 256
    int N   = in_sizes[0] / DIN;           // 100000
    int E   = in_sizes[1] / 2;             // 1600000
    int EL  = in_sizes[2] / 2;             // 200000
    const int* src = ei;
    const int* dst = ei + E;
    const int* ea = eli;
    const int* eb = eli + EL;

    int NB = (N + 255) >> BUCKET_BITS;     // 391 buckets

    // workspace carve-up (256B aligned)
    char* ws = (char*)d_ws;
    size_t off = 0;
    auto alloc = [&](size_t bytes) {
        void* p = ws + off;
        off += (bytes + 255) & ~(size_t)255;
        return p;
    };
    int*   cursor = (int*)alloc(512 * 4);
    int*   rowptr = (int*)alloc((size_t)N * 4);
    int*   deg    = (int*)alloc((size_t)N * 4);
    float* dinv   = (float*)alloc((size_t)N * 4);
    int*   adj    = (int*)alloc((size_t)NB * CAP * 4);      // bucketed, with gaps
    float* buf1   = (float*)alloc((size_t)N * DH * 4);      // pairs staging, then g1/g2
    float* buf2   = (float*)alloc((size_t)N * DH * 4);      // hrelu, then z
    int*   pairs  = (int*)buf1;   // NB*CAP*4 = 8 MB << 51.2 MB; dead before gemm1 writes buf1

    // CSR build (bucket-partitioned)
    init_cursor_kernel<<<2, 256, 0, stream>>>(cursor);
    int blocksA = (E + EPB - 1) / EPB;
    bucket_scatter_kernel<<<blocksA, 256, 0, stream>>>(src, dst, E, cursor, pairs);
    bucket_build_kernel<<<NB, 256, 0, stream>>>(pairs, cursor, rowptr, deg, dinv, adj, N);

    int gemm_blocks = (N + BM - 1) / BM;
    // conv1: g1 = (x @ W1) * dinv
    gemm_scale_kernel<<<gemm_blocks, 256, 0, stream>>>(x, W1, dinv, buf1, N, DIN);
    // hrelu = relu(dinv*(g1_self + sum g1[adj]) + b1)
    agg_kernel<<<N, 128, 0, stream>>>(buf1, rowptr, deg, adj, dinv, b1, buf2, N, 1);
    // conv2: g2 = (hrelu @ W2) * dinv
    gemm_scale_kernel<<<gemm_blocks, 256, 0, stream>>>(buf2, W2, dinv, buf1, N, DHv);
    // z = dinv*(g2_self + sum g2[adj]) + b2
    agg_kernel<<<N, 128, 0, stream>>>(buf1, rowptr, deg, adj, dinv, b2, buf2, N, 0);
    // logits
    decode_kernel<<<(EL * 64 + 255) / 256, 256, 0, stream>>>(buf2, ea, eb, out, EL);
}

// Round 4
// 609.270 us; speedup vs baseline: 1.6452x; 1.0138x over previous
//
#include <hip/hip_runtime.h>
#include <hip/hip_bf16.h>

// GCN link predictor:
//   h = relu(gcnconv(x, W1, b1));  z = gcnconv(h, W2, b2);
//   out[e] = dot(z[eli0[e]], z[eli1[e]])
// g = h*dinv is produced by the GEMM epilogue so aggregation is a plain gather-sum.
//
// R2: bucket-partitioned CSR build (fill_kernel's 105 MB partial-line scatter -> 20 MB runs).
// R3: agg gather vectorized to float4 (32 lanes/node) with 4-edge unroll + 4 acc chains:
//     R2's agg was latency-bound (1 outstanding scalar gather/wave, VALUBusy 24%,
//     3.86 TB/s EA) -> raise MLP to ~4 outstanding 512B gathers/wave.

#define DH 128
#define BUCKET_BITS 8
#define CAP 5120            // per-bucket edge capacity; mean 4096 -> 16 sigma slack
#define EPB 4096            // edges per block in stage A

// ---------------- CSR build ----------------

__global__ __launch_bounds__(256) void init_cursor_kernel(int* __restrict__ cursor) {
    int i = blockIdx.x * 256 + threadIdx.x;    // 512 total
    cursor[i] = i * CAP;
}

// Stage A: partition edges into buckets by dst>>8; packed = src | (dst&255)<<17
// (valid for N <= 131072; here N = 100000).
__global__ __launch_bounds__(256) void bucket_scatter_kernel(
    const int* __restrict__ src, const int* __restrict__ dst, int E,
    int* __restrict__ cursor, int* __restrict__ pairs) {
    __shared__ int hist[512];
    __shared__ int base[512];
    int t = threadIdx.x;
    int e0 = blockIdx.x * EPB;
    hist[t] = 0; hist[t + 256] = 0;
    __syncthreads();
#pragma unroll
    for (int r = 0; r < EPB / 256; r++) {
        int i = e0 + r * 256 + t;
        if (i < E) atomicAdd(&hist[dst[i] >> BUCKET_BITS], 1);
    }
    __syncthreads();
#pragma unroll
    for (int b = t; b < 512; b += 256) {
        int h = hist[b];
        base[b] = h ? atomicAdd(&cursor[b], h) : 0;
    }
    __syncthreads();
    hist[t] = 0; hist[t + 256] = 0;
    __syncthreads();
#pragma unroll
    for (int r = 0; r < EPB / 256; r++) {
        int i = e0 + r * 256 + t;
        if (i < E) {
            int d = dst[i];
            int b = d >> BUCKET_BITS;
            int rk = atomicAdd(&hist[b], 1);
            pairs[base[b] + rk] = src[i] | ((d & 255) << 17);
        }
    }
}

// Stage B: per-bucket CSR finalize. rowptr/deg/dinv via LDS count+scan,
// adj scatter via LDS cursors into this bucket's private region.
__global__ __launch_bounds__(256) void bucket_build_kernel(
    const int* __restrict__ pairs, const int* __restrict__ cursor,
    int* __restrict__ rowptr, int* __restrict__ deg, float* __restrict__ dinv,
    int* __restrict__ adj, int N) {
    __shared__ int cnt[256];
    __shared__ int sc[256];
    __shared__ int basep[256];
    int b = blockIdx.x;
    int t = threadIdx.x;
    int nb0 = b << BUCKET_BITS;
    int p0 = b * CAP;
    int p1 = cursor[b];               // end of this bucket's pairs
    cnt[t] = 0;
    __syncthreads();
    for (int i = p0 + t; i < p1; i += 256)
        atomicAdd(&cnt[pairs[i] >> 17], 1);
    __syncthreads();
    int c = cnt[t];
    sc[t] = c;
    __syncthreads();
    for (int off = 1; off < 256; off <<= 1) {
        int u = (t >= off) ? sc[t - off] : 0;
        __syncthreads();
        sc[t] += u;
        __syncthreads();
    }
    int ex = sc[t] - c;               // exclusive scan within bucket
    int node = nb0 + t;
    if (node < N) {
        rowptr[node] = p0 + ex;
        deg[node]    = c;
        dinv[node]   = rsqrtf((float)(c + 1));
    }
    basep[t] = p0 + ex;
    cnt[t] = 0;
    __syncthreads();
    for (int i = p0 + t; i < p1; i += 256) {
        int v = pairs[i];
        int li = v >> 17;
        int rk = atomicAdd(&cnt[li], 1);
        adj[basep[li] + rk] = v & 0x1FFFF;
    }
}

// ---------------- GEMM: out[m][n] = (sum_k A[m][k]*B[k][n]) * dinv[m], N=128 ----------------

#define BM 128
#define BK 16

__global__ __launch_bounds__(256) void gemm_scale_kernel(
    const float* __restrict__ A, const float* __restrict__ B,
    const float* __restrict__ dinv, float* __restrict__ out,
    int M, int K) {
    __shared__ float Alds[BK][BM + 4];   // transposed: Alds[k][m]
    __shared__ float Blds[BK][DH];
    int t  = threadIdx.x;
    int tx = t % 16;       // column group (8 cols each)
    int ty = t / 16;       // row group (8 rows each)
    int m0 = blockIdx.x * BM;
    float acc[8][8];
#pragma unroll
    for (int i = 0; i < 8; i++)
#pragma unroll
        for (int j = 0; j < 8; j++) acc[i][j] = 0.f;

    for (int k0 = 0; k0 < K; k0 += BK) {
#pragma unroll
        for (int l = 0; l < 2; l++) {
            int lin = t + l * 256;        // 0..511
            int row = lin >> 2;           // m within tile, 0..127
            int c4  = lin & 3;            // float4 along k
            int m = m0 + row;
            float4 v = make_float4(0.f, 0.f, 0.f, 0.f);
            if (m < M) v = *(const float4*)&A[(size_t)m * K + k0 + c4 * 4];
            Alds[c4 * 4 + 0][row] = v.x;
            Alds[c4 * 4 + 1][row] = v.y;
            Alds[c4 * 4 + 2][row] = v.z;
            Alds[c4 * 4 + 3][row] = v.w;
        }
#pragma unroll
        for (int l = 0; l < 2; l++) {
            int lin = t + l * 256;
            int row = lin >> 5;           // k 0..15
            int c4  = lin & 31;           // float4 along n
            *(float4*)&Blds[row][c4 * 4] = *(const float4*)&B[(size_t)(k0 + row) * DH + c4 * 4];
        }
        __syncthreads();
#pragma unroll
        for (int kk = 0; kk < BK; kk++) {
            float a[8], bb[8];
            *(float4*)&a[0]  = *(const float4*)&Alds[kk][ty * 8];
            *(float4*)&a[4]  = *(const float4*)&Alds[kk][ty * 8 + 4];
            *(float4*)&bb[0] = *(const float4*)&Blds[kk][tx * 8];
            *(float4*)&bb[4] = *(const float4*)&Blds[kk][tx * 8 + 4];
#pragma unroll
            for (int i = 0; i < 8; i++)
#pragma unroll
                for (int j = 0; j < 8; j++)
                    acc[i][j] = fmaf(a[i], bb[j], acc[i][j]);
        }
        __syncthreads();
    }
#pragma unroll
    for (int i = 0; i < 8; i++) {
        int m = m0 + ty * 8 + i;
        if (m < M) {
            float s = dinv[m];
            float4 v0 = make_float4(acc[i][0] * s, acc[i][1] * s, acc[i][2] * s, acc[i][3] * s);
            float4 v1 = make_float4(acc[i][4] * s, acc[i][5] * s, acc[i][6] * s, acc[i][7] * s);
            *(float4*)&out[(size_t)m * DH + tx * 8]     = v0;
            *(float4*)&out[(size_t)m * DH + tx * 8 + 4] = v1;
        }
    }
}

// ---------------- Aggregation ----------------
// out[i] = dinv[i]*(g[i] + sum_j g[adj]) + b, optional relu.
// 32-lane group per node, float4/lane covers 128 ch; 4-edge unroll, 4 acc chains.

#define NPB 8    // nodes (32-lane groups) per 256-thread block

__device__ __forceinline__ void f4acc(float4& a, const float4 v) {
    a.x += v.x; a.y += v.y; a.z += v.z; a.w += v.w;
}

__global__ __launch_bounds__(256) void agg_kernel(
    const float* __restrict__ g, const int* __restrict__ rowptr,
    const int* __restrict__ deg, const int* __restrict__ adj,
    const float* __restrict__ dinv, const float* __restrict__ bias,
    float* __restrict__ out, int N, int do_relu) {
    int grp = threadIdx.x >> 5;
    int l   = threadIdx.x & 31;
    int c4  = l * 4;
    int i = blockIdx.x * NPB + grp;
    if (i >= N) return;
    int r0 = rowptr[i];
    int d  = deg[i];
    float4 a0 = *(const float4*)(g + (size_t)i * DH + c4);   // self term
    float4 a1 = make_float4(0.f, 0.f, 0.f, 0.f);
    float4 a2 = make_float4(0.f, 0.f, 0.f, 0.f);
    float4 a3 = make_float4(0.f, 0.f, 0.f, 0.f);
    int r = 0;
    for (; r + 4 <= d; r += 4) {
        int j0 = adj[r0 + r];
        int j1 = adj[r0 + r + 1];
        int j2 = adj[r0 + r + 2];
        int j3 = adj[r0 + r + 3];
        float4 v0 = *(const float4*)(g + (size_t)j0 * DH + c4);
        float4 v1 = *(const float4*)(g + (size_t)j1 * DH + c4);
        float4 v2 = *(const float4*)(g + (size_t)j2 * DH + c4);
        float4 v3 = *(const float4*)(g + (size_t)j3 * DH + c4);
        f4acc(a0, v0); f4acc(a1, v1); f4acc(a2, v2); f4acc(a3, v3);
    }
    for (; r < d; r++) {
        int j = adj[r0 + r];
        f4acc(a0, *(const float4*)(g + (size_t)j * DH + c4));
    }
    f4acc(a0, a1); f4acc(a2, a3); f4acc(a0, a2);
    float dv = dinv[i];
    float4 bv = *(const float4*)(bias + c4);
    float4 s;
    s.x = a0.x * dv + bv.x;
    s.y = a0.y * dv + bv.y;
    s.z = a0.z * dv + bv.z;
    s.w = a0.w * dv + bv.w;
    if (do_relu) {
        s.x = fmaxf(s.x, 0.f); s.y = fmaxf(s.y, 0.f);
        s.z = fmaxf(s.z, 0.f); s.w = fmaxf(s.w, 0.f);
    }
    *(float4*)(out + (size_t)i * DH + c4) = s;
}

// ---------------- Decode: out[e] = dot(z[a], z[b]) over 128 ----------------
// 32-lane group per edge, float4/lane, width-32 shuffle reduce.

__global__ __launch_bounds__(256) void decode_kernel(
    const float* __restrict__ z, const int* __restrict__ ea, const int* __restrict__ eb,
    float* __restrict__ out, int EL) {
    int e = blockIdx.x * 8 + (threadIdx.x >> 5);
    int l = threadIdx.x & 31;
    if (e >= EL) return;
    int a = ea[e], b = eb[e];
    float4 va = *(const float4*)(z + (size_t)a * DH + l * 4);
    float4 vb = *(const float4*)(z + (size_t)b * DH + l * 4);
    float acc = va.x * vb.x + va.y * vb.y + va.z * vb.z + va.w * vb.w;
#pragma unroll
    for (int off = 16; off > 0; off >>= 1)
        acc += __shfl_down(acc, off, 32);
    if (l == 0) out[e] = acc;
}

// ---------------- Launch ----------------

extern "C" void kernel_launch(void* const* d_in, const int* in_sizes, int n_in,
                              void* d_out, int out_size, void* d_ws, size_t ws_size,
                              hipStream_t stream) {
    const float* x   = (const float*)d_in[0];
    const int*   ei  = (const int*)d_in[1];
    const int*   eli = (const int*)d_in[2];
    const float* W1  = (const float*)d_in[3];
    const float* b1  = (const float*)d_in[4];
    const float* W2  = (const float*)d_in[5];
    const float* b2  = (const float*)d_in[6];
    float* out = (float*)d_out;

    int DHv = in_sizes[4];                 // 128
    int DIN = in_sizes[3] / DHv;           // 256
    int N   = in_sizes[0] / DIN;           // 100000
    int E   = in_sizes[1] / 2;             // 1600000
    int EL  = in_sizes[2] / 2;             // 200000
    const int* src = ei;
    const int* dst = ei + E;
    const int* ea = eli;
    const int* eb = eli + EL;

    int NB = (N + 255) >> BUCKET_BITS;     // 391 buckets

    // workspace carve-up (256B aligned)
    char* ws = (char*)d_ws;
    size_t off = 0;
    auto alloc = [&](size_t bytes) {
        void* p = ws + off;
        off += (bytes + 255) & ~(size_t)255;
        return p;
    };
    int*   cursor = (int*)alloc(512 * 4);
    int*   rowptr = (int*)alloc((size_t)N * 4);
    int*   deg    = (int*)alloc((size_t)N * 4);
    float* dinv   = (float*)alloc((size_t)N * 4);
    int*   adj    = (int*)alloc((size_t)NB * CAP * 4);      // bucketed, with gaps
    float* buf1   = (float*)alloc((size_t)N * DH * 4);      // pairs staging, then g1/g2
    float* buf2   = (float*)alloc((size_t)N * DH * 4);      // hrelu, then z
    int*   pairs  = (int*)buf1;   // NB*CAP*4 = 8 MB << 51.2 MB; dead before gemm1 writes buf1

    // CSR build (bucket-partitioned)
    init_cursor_kernel<<<2, 256, 0, stream>>>(cursor);
    int blocksA = (E + EPB - 1) / EPB;
    bucket_scatter_kernel<<<blocksA, 256, 0, stream>>>(src, dst, E, cursor, pairs);
    bucket_build_kernel<<<NB, 256, 0, stream>>>(pairs, cursor, rowptr, deg, dinv, adj, N);

    int gemm_blocks = (N + BM - 1) / BM;
    // conv1: g1 = (x @ W1) * dinv
    gemm_scale_kernel<<<gemm_blocks, 256, 0, stream>>>(x, W1, dinv, buf1, N, DIN);
    // hrelu = relu(dinv*(g1_self + sum g1[adj]) + b1)
    agg_kernel<<<(N + NPB - 1) / NPB, 256, 0, stream>>>(buf1, rowptr, deg, adj, dinv, b1, buf2, N, 1);
    // conv2: g2 = (hrelu @ W2) * dinv
    gemm_scale_kernel<<<gemm_blocks, 256, 0, stream>>>(buf2, W2, dinv, buf1, N, DHv);
    // z = dinv*(g2_self + sum g2[adj]) + b2
    agg_kernel<<<(N + NPB - 1) / NPB, 256, 0, stream>>>(buf1, rowptr, deg, adj, dinv, b2, buf2, N, 0);
    // logits
    decode_kernel<<<(EL + 7) / 8, 256, 0, stream>>>(buf2, ea, eb, out, EL);
}

// Round 5
// 524.951 us; speedup vs baseline: 1.9094x; 1.1606x over previous
//
#include <hip/hip_runtime.h>
#include <hip/hip_bf16.h>

// GCN link predictor:
//   h = relu(gcnconv(x, W1, b1));  z = gcnconv(h, W2, b2);
//   out[e] = dot(z[eli0[e]], z[eli1[e]])
// g = h*dinv is produced by the GEMM epilogue so aggregation is a plain gather-sum.
//
// R2: bucket-partitioned CSR build (fill_kernel's 105 MB partial-line scatter -> 20 MB runs).
// R3: float4 gather + unroll was NEUTRAL: agg pinned at ~122 us by L2-miss byte rate
//     (~400 MB misses of 819 MB demand; two different kernel shapes, same time).
// R4: g buffers stored as bf16 (RNE in GEMM epilogue): per-edge gather 512B->256B,
//     halving both demand and L2-miss traffic. Accumulation/outputs stay fp32.

#define DH 128
#define BUCKET_BITS 8
#define CAP 5120            // per-bucket edge capacity; mean 4096 -> 16 sigma slack
#define EPB 4096            // edges per block in stage A

typedef unsigned short bf16_t;
typedef unsigned int uint32;

__device__ __forceinline__ uint32 bfpack(float f) {   // fp32 -> bf16 bits, RNE
    uint32 b = __float_as_uint(f);
    return (b + 0x7fffu + ((b >> 16) & 1u)) >> 16;
}

__device__ __forceinline__ float4 bf4(uint2 u) {      // 4 packed bf16 -> float4
    float4 f;
    f.x = __uint_as_float(u.x << 16);
    f.y = __uint_as_float(u.x & 0xffff0000u);
    f.z = __uint_as_float(u.y << 16);
    f.w = __uint_as_float(u.y & 0xffff0000u);
    return f;
}

// ---------------- CSR build ----------------

__global__ __launch_bounds__(256) void init_cursor_kernel(int* __restrict__ cursor) {
    int i = blockIdx.x * 256 + threadIdx.x;    // 512 total
    cursor[i] = i * CAP;
}

// Stage A: partition edges into buckets by dst>>8; packed = src | (dst&255)<<17
// (valid for N <= 131072; here N = 100000).
__global__ __launch_bounds__(256) void bucket_scatter_kernel(
    const int* __restrict__ src, const int* __restrict__ dst, int E,
    int* __restrict__ cursor, int* __restrict__ pairs) {
    __shared__ int hist[512];
    __shared__ int base[512];
    int t = threadIdx.x;
    int e0 = blockIdx.x * EPB;
    hist[t] = 0; hist[t + 256] = 0;
    __syncthreads();
#pragma unroll
    for (int r = 0; r < EPB / 256; r++) {
        int i = e0 + r * 256 + t;
        if (i < E) atomicAdd(&hist[dst[i] >> BUCKET_BITS], 1);
    }
    __syncthreads();
#pragma unroll
    for (int b = t; b < 512; b += 256) {
        int h = hist[b];
        base[b] = h ? atomicAdd(&cursor[b], h) : 0;
    }
    __syncthreads();
    hist[t] = 0; hist[t + 256] = 0;
    __syncthreads();
#pragma unroll
    for (int r = 0; r < EPB / 256; r++) {
        int i = e0 + r * 256 + t;
        if (i < E) {
            int d = dst[i];
            int b = d >> BUCKET_BITS;
            int rk = atomicAdd(&hist[b], 1);
            pairs[base[b] + rk] = src[i] | ((d & 255) << 17);
        }
    }
}

// Stage B: per-bucket CSR finalize. rowptr/deg/dinv via LDS count+scan,
// adj scatter via LDS cursors into this bucket's private region.
__global__ __launch_bounds__(256) void bucket_build_kernel(
    const int* __restrict__ pairs, const int* __restrict__ cursor,
    int* __restrict__ rowptr, int* __restrict__ deg, float* __restrict__ dinv,
    int* __restrict__ adj, int N) {
    __shared__ int cnt[256];
    __shared__ int sc[256];
    __shared__ int basep[256];
    int b = blockIdx.x;
    int t = threadIdx.x;
    int nb0 = b << BUCKET_BITS;
    int p0 = b * CAP;
    int p1 = cursor[b];               // end of this bucket's pairs
    cnt[t] = 0;
    __syncthreads();
    for (int i = p0 + t; i < p1; i += 256)
        atomicAdd(&cnt[pairs[i] >> 17], 1);
    __syncthreads();
    int c = cnt[t];
    sc[t] = c;
    __syncthreads();
    for (int off = 1; off < 256; off <<= 1) {
        int u = (t >= off) ? sc[t - off] : 0;
        __syncthreads();
        sc[t] += u;
        __syncthreads();
    }
    int ex = sc[t] - c;               // exclusive scan within bucket
    int node = nb0 + t;
    if (node < N) {
        rowptr[node] = p0 + ex;
        deg[node]    = c;
        dinv[node]   = rsqrtf((float)(c + 1));
    }
    basep[t] = p0 + ex;
    cnt[t] = 0;
    __syncthreads();
    for (int i = p0 + t; i < p1; i += 256) {
        int v = pairs[i];
        int li = v >> 17;
        int rk = atomicAdd(&cnt[li], 1);
        adj[basep[li] + rk] = v & 0x1FFFF;
    }
}

// ---------------- GEMM: out[m][n] = bf16((sum_k A[m][k]*B[k][n]) * dinv[m]), N=128 ----------

#define BM 128
#define BK 16

__global__ __launch_bounds__(256) void gemm_scale_kernel(
    const float* __restrict__ A, const float* __restrict__ B,
    const float* __restrict__ dinv, bf16_t* __restrict__ out,
    int M, int K) {
    __shared__ float Alds[BK][BM + 4];   // transposed: Alds[k][m]
    __shared__ float Blds[BK][DH];
    int t  = threadIdx.x;
    int tx = t % 16;       // column group (8 cols each)
    int ty = t / 16;       // row group (8 rows each)
    int m0 = blockIdx.x * BM;
    float acc[8][8];
#pragma unroll
    for (int i = 0; i < 8; i++)
#pragma unroll
        for (int j = 0; j < 8; j++) acc[i][j] = 0.f;

    for (int k0 = 0; k0 < K; k0 += BK) {
#pragma unroll
        for (int l = 0; l < 2; l++) {
            int lin = t + l * 256;        // 0..511
            int row = lin >> 2;           // m within tile, 0..127
            int c4  = lin & 3;            // float4 along k
            int m = m0 + row;
            float4 v = make_float4(0.f, 0.f, 0.f, 0.f);
            if (m < M) v = *(const float4*)&A[(size_t)m * K + k0 + c4 * 4];
            Alds[c4 * 4 + 0][row] = v.x;
            Alds[c4 * 4 + 1][row] = v.y;
            Alds[c4 * 4 + 2][row] = v.z;
            Alds[c4 * 4 + 3][row] = v.w;
        }
#pragma unroll
        for (int l = 0; l < 2; l++) {
            int lin = t + l * 256;
            int row = lin >> 5;           // k 0..15
            int c4  = lin & 31;           // float4 along n
            *(float4*)&Blds[row][c4 * 4] = *(const float4*)&B[(size_t)(k0 + row) * DH + c4 * 4];
        }
        __syncthreads();
#pragma unroll
        for (int kk = 0; kk < BK; kk++) {
            float a[8], bb[8];
            *(float4*)&a[0]  = *(const float4*)&Alds[kk][ty * 8];
            *(float4*)&a[4]  = *(const float4*)&Alds[kk][ty * 8 + 4];
            *(float4*)&bb[0] = *(const float4*)&Blds[kk][tx * 8];
            *(float4*)&bb[4] = *(const float4*)&Blds[kk][tx * 8 + 4];
#pragma unroll
            for (int i = 0; i < 8; i++)
#pragma unroll
                for (int j = 0; j < 8; j++)
                    acc[i][j] = fmaf(a[i], bb[j], acc[i][j]);
        }
        __syncthreads();
    }
#pragma unroll
    for (int i = 0; i < 8; i++) {
        int m = m0 + ty * 8 + i;
        if (m < M) {
            float s = dinv[m];
            uint32 p0 = bfpack(acc[i][0] * s) | (bfpack(acc[i][1] * s) << 16);
            uint32 p1 = bfpack(acc[i][2] * s) | (bfpack(acc[i][3] * s) << 16);
            uint32 p2 = bfpack(acc[i][4] * s) | (bfpack(acc[i][5] * s) << 16);
            uint32 p3 = bfpack(acc[i][6] * s) | (bfpack(acc[i][7] * s) << 16);
            *(uint4*)&out[(size_t)m * DH + tx * 8] = make_uint4(p0, p1, p2, p3);
        }
    }
}

// ---------------- Aggregation ----------------
// out[i] = dinv[i]*(g[i] + sum_j g[adj]) + b, optional relu. g is bf16 (256 B/row).
// 32-lane group per node, uint2 (4 bf16)/lane; 4-edge unroll, 4 fp32 acc chains.

#define NPB 8    // nodes (32-lane groups) per 256-thread block

__device__ __forceinline__ void f4acc(float4& a, const float4 v) {
    a.x += v.x; a.y += v.y; a.z += v.z; a.w += v.w;
}

__global__ __launch_bounds__(256) void agg_kernel(
    const bf16_t* __restrict__ g, const int* __restrict__ rowptr,
    const int* __restrict__ deg, const int* __restrict__ adj,
    const float* __restrict__ dinv, const float* __restrict__ bias,
    float* __restrict__ out, int N, int do_relu) {
    int grp = threadIdx.x >> 5;
    int l   = threadIdx.x & 31;
    int c4  = l * 4;
    int i = blockIdx.x * NPB + grp;
    if (i >= N) return;
    int r0 = rowptr[i];
    int d  = deg[i];
    float4 a0 = bf4(*(const uint2*)(g + (size_t)i * DH + c4));   // self term
    float4 a1 = make_float4(0.f, 0.f, 0.f, 0.f);
    float4 a2 = make_float4(0.f, 0.f, 0.f, 0.f);
    float4 a3 = make_float4(0.f, 0.f, 0.f, 0.f);
    int r = 0;
    for (; r + 4 <= d; r += 4) {
        int j0 = adj[r0 + r];
        int j1 = adj[r0 + r + 1];
        int j2 = adj[r0 + r + 2];
        int j3 = adj[r0 + r + 3];
        uint2 u0 = *(const uint2*)(g + (size_t)j0 * DH + c4);
        uint2 u1 = *(const uint2*)(g + (size_t)j1 * DH + c4);
        uint2 u2 = *(const uint2*)(g + (size_t)j2 * DH + c4);
        uint2 u3 = *(const uint2*)(g + (size_t)j3 * DH + c4);
        f4acc(a0, bf4(u0)); f4acc(a1, bf4(u1)); f4acc(a2, bf4(u2)); f4acc(a3, bf4(u3));
    }
    for (; r < d; r++) {
        int j = adj[r0 + r];
        f4acc(a0, bf4(*(const uint2*)(g + (size_t)j * DH + c4)));
    }
    f4acc(a0, a1); f4acc(a2, a3); f4acc(a0, a2);
    float dv = dinv[i];
    float4 bv = *(const float4*)(bias + c4);
    float4 s;
    s.x = a0.x * dv + bv.x;
    s.y = a0.y * dv + bv.y;
    s.z = a0.z * dv + bv.z;
    s.w = a0.w * dv + bv.w;
    if (do_relu) {
        s.x = fmaxf(s.x, 0.f); s.y = fmaxf(s.y, 0.f);
        s.z = fmaxf(s.z, 0.f); s.w = fmaxf(s.w, 0.f);
    }
    *(float4*)(out + (size_t)i * DH + c4) = s;
}

// ---------------- Decode: out[e] = dot(z[a], z[b]) over 128 (z fp32) ----------------

__global__ __launch_bounds__(256) void decode_kernel(
    const float* __restrict__ z, const int* __restrict__ ea, const int* __restrict__ eb,
    float* __restrict__ out, int EL) {
    int e = blockIdx.x * 8 + (threadIdx.x >> 5);
    int l = threadIdx.x & 31;
    if (e >= EL) return;
    int a = ea[e], b = eb[e];
    float4 va = *(const float4*)(z + (size_t)a * DH + l * 4);
    float4 vb = *(const float4*)(z + (size_t)b * DH + l * 4);
    float acc = va.x * vb.x + va.y * vb.y + va.z * vb.z + va.w * vb.w;
#pragma unroll
    for (int off = 16; off > 0; off >>= 1)
        acc += __shfl_down(acc, off, 32);
    if (l == 0) out[e] = acc;
}

// ---------------- Launch ----------------

extern "C" void kernel_launch(void* const* d_in, const int* in_sizes, int n_in,
                              void* d_out, int out_size, void* d_ws, size_t ws_size,
                              hipStream_t stream) {
    const float* x   = (const float*)d_in[0];
    const int*   ei  = (const int*)d_in[1];
    const int*   eli = (const int*)d_in[2];
    const float* W1  = (const float*)d_in[3];
    const float* b1  = (const float*)d_in[4];
    const float* W2  = (const float*)d_in[5];
    const float* b2  = (const float*)d_in[6];
    float* out = (float*)d_out;

    int DHv = in_sizes[4];                 // 128
    int DIN = in_sizes[3] / DHv;           // 256
    int N   = in_sizes[0] / DIN;           // 100000
    int E   = in_sizes[1] / 2;             // 1600000
    int EL  = in_sizes[2] / 2;             // 200000
    const int* src = ei;
    const int* dst = ei + E;
    const int* ea = eli;
    const int* eb = eli + EL;

    int NB = (N + 255) >> BUCKET_BITS;     // 391 buckets

    // workspace carve-up (256B aligned)
    char* ws = (char*)d_ws;
    size_t off = 0;
    auto alloc = [&](size_t bytes) {
        void* p = ws + off;
        off += (bytes + 255) & ~(size_t)255;
        return p;
    };
    int*    cursor = (int*)alloc(512 * 4);
    int*    rowptr = (int*)alloc((size_t)N * 4);
    int*    deg    = (int*)alloc((size_t)N * 4);
    float*  dinv   = (float*)alloc((size_t)N * 4);
    int*    adj    = (int*)alloc((size_t)NB * CAP * 4);     // bucketed, with gaps
    bf16_t* gbuf   = (bf16_t*)alloc((size_t)N * DH * 2);    // g1, then g2 (bf16)
    float*  bufh   = (float*)alloc((size_t)N * DH * 4);     // hrelu, then z (fp32)
    int*    pairs  = (int*)bufh;   // 8 MB staging; dead before agg1 writes bufh

    // CSR build (bucket-partitioned)
    init_cursor_kernel<<<2, 256, 0, stream>>>(cursor);
    int blocksA = (E + EPB - 1) / EPB;
    bucket_scatter_kernel<<<blocksA, 256, 0, stream>>>(src, dst, E, cursor, pairs);
    bucket_build_kernel<<<NB, 256, 0, stream>>>(pairs, cursor, rowptr, deg, dinv, adj, N);

    int gemm_blocks = (N + BM - 1) / BM;
    // conv1: g1 = bf16((x @ W1) * dinv)
    gemm_scale_kernel<<<gemm_blocks, 256, 0, stream>>>(x, W1, dinv, gbuf, N, DIN);
    // hrelu = relu(dinv*(g1_self + sum g1[adj]) + b1)   [fp32]
    agg_kernel<<<(N + NPB - 1) / NPB, 256, 0, stream>>>(gbuf, rowptr, deg, adj, dinv, b1, bufh, N, 1);
    // conv2: g2 = bf16((hrelu @ W2) * dinv)
    gemm_scale_kernel<<<gemm_blocks, 256, 0, stream>>>(bufh, W2, dinv, gbuf, N, DHv);
    // z = dinv*(g2_self + sum g2[adj]) + b2   [fp32, overwrites hrelu]
    agg_kernel<<<(N + NPB - 1) / NPB, 256, 0, stream>>>(gbuf, rowptr, deg, adj, dinv, b2, bufh, N, 0);
    // logits
    decode_kernel<<<(EL + 7) / 8, 256, 0, stream>>>(bufh, ea, eb, out, EL);
}

// Round 6
// 410.919 us; speedup vs baseline: 2.4393x; 1.2775x over previous
//
#include <hip/hip_runtime.h>
#include <hip/hip_bf16.h>

// GCN link predictor:
//   h = relu(gcnconv(x, W1, b1));  z = gcnconv(h, W2, b2);
//   out[e] = dot(z[eli0[e]], z[eli1[e]])
// g = (x@W)*dinv is produced by the GEMM epilogue so aggregation is a plain gather-sum.
//
// R2: bucket-partitioned CSR build (kills 105 MB partial-line scatter).
// R3: float4 gather + unroll: NEUTRAL (agg is L2-miss byte-rate bound).
// R4: g buffers 16-bit: halves gather bytes -> agg ~2x faster.
// R5: GEMMs -> MFMA f16 (fp32 GEMM was 137 us: VALUBusy 40%, 7.2M LDS conflicts).
//     All 16-bit tensors switch bf16->fp16 (4x better mantissa, same bytes):
//     g fp16, hrelu fp16 (feeds GEMM2 A), z fp16 (halves decode gather traffic).

#define DH 128
#define BUCKET_BITS 8
#define CAP 5120            // per-bucket edge capacity; mean 4096 -> 16 sigma slack
#define EPB 4096            // edges per block in stage A
#define KPAD 40             // LDS row stride in halves (80 B: conflict-free b128 frags)

typedef _Float16 half8 __attribute__((ext_vector_type(8)));
typedef float floatx4 __attribute__((ext_vector_type(4)));

// ---------------- CSR build ----------------

__global__ __launch_bounds__(256) void init_cursor_kernel(int* __restrict__ cursor) {
    int i = blockIdx.x * 256 + threadIdx.x;    // 512 total
    cursor[i] = i * CAP;
}

// Stage A: partition edges into buckets by dst>>8; packed = src | (dst&255)<<17
// (valid for N <= 131072; here N = 100000).
__global__ __launch_bounds__(256) void bucket_scatter_kernel(
    const int* __restrict__ src, const int* __restrict__ dst, int E,
    int* __restrict__ cursor, int* __restrict__ pairs) {
    __shared__ int hist[512];
    __shared__ int base[512];
    int t = threadIdx.x;
    int e0 = blockIdx.x * EPB;
    hist[t] = 0; hist[t + 256] = 0;
    __syncthreads();
#pragma unroll
    for (int r = 0; r < EPB / 256; r++) {
        int i = e0 + r * 256 + t;
        if (i < E) atomicAdd(&hist[dst[i] >> BUCKET_BITS], 1);
    }
    __syncthreads();
#pragma unroll
    for (int b = t; b < 512; b += 256) {
        int h = hist[b];
        base[b] = h ? atomicAdd(&cursor[b], h) : 0;
    }
    __syncthreads();
    hist[t] = 0; hist[t + 256] = 0;
    __syncthreads();
#pragma unroll
    for (int r = 0; r < EPB / 256; r++) {
        int i = e0 + r * 256 + t;
        if (i < E) {
            int d = dst[i];
            int b = d >> BUCKET_BITS;
            int rk = atomicAdd(&hist[b], 1);
            pairs[base[b] + rk] = src[i] | ((d & 255) << 17);
        }
    }
}

// Stage B: per-bucket CSR finalize. rowptr/deg/dinv via LDS count+scan,
// adj scatter via LDS cursors into this bucket's private region.
__global__ __launch_bounds__(256) void bucket_build_kernel(
    const int* __restrict__ pairs, const int* __restrict__ cursor,
    int* __restrict__ rowptr, int* __restrict__ deg, float* __restrict__ dinv,
    int* __restrict__ adj, int N) {
    __shared__ int cnt[256];
    __shared__ int sc[256];
    __shared__ int basep[256];
    int b = blockIdx.x;
    int t = threadIdx.x;
    int nb0 = b << BUCKET_BITS;
    int p0 = b * CAP;
    int p1 = cursor[b];               // end of this bucket's pairs
    cnt[t] = 0;
    __syncthreads();
    for (int i = p0 + t; i < p1; i += 256)
        atomicAdd(&cnt[pairs[i] >> 17], 1);
    __syncthreads();
    int c = cnt[t];
    sc[t] = c;
    __syncthreads();
    for (int off = 1; off < 256; off <<= 1) {
        int u = (t >= off) ? sc[t - off] : 0;
        __syncthreads();
        sc[t] += u;
        __syncthreads();
    }
    int ex = sc[t] - c;               // exclusive scan within bucket
    int node = nb0 + t;
    if (node < N) {
        rowptr[node] = p0 + ex;
        deg[node]    = c;
        dinv[node]   = rsqrtf((float)(c + 1));
    }
    basep[t] = p0 + ex;
    cnt[t] = 0;
    __syncthreads();
    for (int i = p0 + t; i < p1; i += 256) {
        int v = pairs[i];
        int li = v >> 17;
        int rk = atomicAdd(&cnt[li], 1);
        adj[basep[li] + rk] = v & 0x1FFFF;
    }
}

// ---------------- Weight transpose+cast: WT[n][k] = fp16(W[k][n]) ----------------
// One 32k x 128n tile per block via LDS.

__global__ __launch_bounds__(256) void wcast_kernel(
    const float* __restrict__ W, _Float16* __restrict__ WT, int K) {
    __shared__ float T[32][132];
    int t = threadIdx.x;
    int k0 = blockIdx.x * 32;
    {
        int kr = t >> 3;              // 0..31
        int c0 = (t & 7) * 16;        // 16 cols per thread
#pragma unroll
        for (int j = 0; j < 4; j++) {
            float4 v = *(const float4*)&W[(size_t)(k0 + kr) * DH + c0 + j * 4];
            T[kr][c0 + j * 4 + 0] = v.x;
            T[kr][c0 + j * 4 + 1] = v.y;
            T[kr][c0 + j * 4 + 2] = v.z;
            T[kr][c0 + j * 4 + 3] = v.w;
        }
    }
    __syncthreads();
    int n  = t >> 1;
    int ko = (t & 1) * 16;
    union { _Float16 h[16]; uint4 u4[2]; } p;
#pragma unroll
    for (int j = 0; j < 16; j++) p.h[j] = (_Float16)T[ko + j][n];
    *(uint4*)&WT[(size_t)n * K + k0 + ko]     = p.u4[0];
    *(uint4*)&WT[(size_t)n * K + k0 + ko + 8] = p.u4[1];
}

// ---------------- MFMA GEMM: out[m][n] = fp16((sum_k A[m][k]*W[k][n]) * dinv[m]) --------
// BM=128, BN=128 (=DH), BK=32. 4 waves; wave owns 32 rows (2 m-tiles), all 8 n-tiles.
// mfma_f32_16x16x32_f16(weightfrag, xfrag, acc): D rows=n, cols=m.
// Frag layout (m97-verified): operand own-dim = lane&15, k = (lane>>4)*8+j;
// C/D: col = lane&15, row = (lane>>4)*4 + reg.

template <int A_FP16>
__global__ __launch_bounds__(256) void gemm_mfma_kernel(
    const void* __restrict__ Ain, const _Float16* __restrict__ WT,
    const float* __restrict__ dinv, _Float16* __restrict__ out,
    int M, int K) {
    __shared__ __attribute__((aligned(16))) _Float16 Alds[128 * KPAD];
    __shared__ __attribute__((aligned(16))) _Float16 Blds[128 * KPAD];
    int t = threadIdx.x;
    int w = t >> 6, l = t & 63;
    int r = l & 15, q = l >> 4;
    int m0 = blockIdx.x * 128;
    int sm  = t >> 1;              // staging row (m for A, n for B)
    int sko = (t & 1) * 16;        // staging k offset (16 halves per thread half-row)

    floatx4 acc[2][8];
#pragma unroll
    for (int mt = 0; mt < 2; mt++)
#pragma unroll
        for (int nt = 0; nt < 8; nt++) acc[mt][nt] = (floatx4)0.f;

    for (int k0 = 0; k0 < K; k0 += 32) {
        // stage B (weights, already fp16 [n][K])
        {
            const _Float16* bs = WT + (size_t)sm * K + k0 + sko;
            *(uint4*)&Blds[sm * KPAD + sko]     = *(const uint4*)bs;
            *(uint4*)&Blds[sm * KPAD + sko + 8] = *(const uint4*)(bs + 8);
        }
        // stage A (cast fp32->fp16 in flight, or copy fp16)
        {
            int m = m0 + sm;
            union { _Float16 h[16]; uint4 u4[2]; } p;
            if (A_FP16) {
                if (m < M) {
                    const _Float16* as = (const _Float16*)Ain + (size_t)m * K + k0 + sko;
                    p.u4[0] = *(const uint4*)as;
                    p.u4[1] = *(const uint4*)(as + 8);
                } else { p.u4[0] = make_uint4(0,0,0,0); p.u4[1] = make_uint4(0,0,0,0); }
            } else {
                if (m < M) {
                    const float* as = (const float*)Ain + (size_t)m * K + k0 + sko;
#pragma unroll
                    for (int j = 0; j < 4; j++) {
                        float4 v = *(const float4*)(as + j * 4);
                        p.h[j*4+0] = (_Float16)v.x; p.h[j*4+1] = (_Float16)v.y;
                        p.h[j*4+2] = (_Float16)v.z; p.h[j*4+3] = (_Float16)v.w;
                    }
                } else { p.u4[0] = make_uint4(0,0,0,0); p.u4[1] = make_uint4(0,0,0,0); }
            }
            *(uint4*)&Alds[sm * KPAD + sko]     = p.u4[0];
            *(uint4*)&Alds[sm * KPAD + sko + 8] = p.u4[1];
        }
        __syncthreads();

        half8 bfr[8];
#pragma unroll
        for (int nt = 0; nt < 8; nt++)
            bfr[nt] = *(const half8*)&Blds[(nt * 16 + r) * KPAD + q * 8];
#pragma unroll
        for (int mt = 0; mt < 2; mt++) {
            half8 afr = *(const half8*)&Alds[(w * 32 + mt * 16 + r) * KPAD + q * 8];
#pragma unroll
            for (int nt = 0; nt < 8; nt++)
                acc[mt][nt] = __builtin_amdgcn_mfma_f32_16x16x32_f16(bfr[nt], afr, acc[mt][nt], 0, 0, 0);
        }
        __syncthreads();
    }

    // epilogue: lane holds m = strip + (l&15); n = nt*16 + q*4 + reg (4 consecutive)
#pragma unroll
    for (int mt = 0; mt < 2; mt++) {
        int m = m0 + w * 32 + mt * 16 + r;
        if (m < M) {
            float dv = dinv[m];
#pragma unroll
            for (int nt = 0; nt < 8; nt++) {
                union { _Float16 h[4]; uint2 u; } p;
#pragma unroll
                for (int reg = 0; reg < 4; reg++)
                    p.h[reg] = (_Float16)(acc[mt][nt][reg] * dv);
                *(uint2*)&out[(size_t)m * DH + nt * 16 + q * 4] = p.u;
            }
        }
    }
}

// ---------------- Aggregation ----------------
// out[i] = dinv[i]*(g[i] + sum_j g[adj]) + b. g fp16 (256 B/row).
// 32-lane group per node, uint2 (4 halves)/lane; 4-edge unroll, 4 fp32 acc chains.
// mode bit0: relu, bit1: write fp16 (else fp32).

#define NPB 8    // nodes (32-lane groups) per 256-thread block

__device__ __forceinline__ float4 h4f(uint2 uu) {
    union { uint2 u; _Float16 h[4]; } c; c.u = uu;
    return make_float4((float)c.h[0], (float)c.h[1], (float)c.h[2], (float)c.h[3]);
}

__device__ __forceinline__ void f4acc(float4& a, const float4 v) {
    a.x += v.x; a.y += v.y; a.z += v.z; a.w += v.w;
}

__global__ __launch_bounds__(256) void agg_kernel(
    const _Float16* __restrict__ g, const int* __restrict__ rowptr,
    const int* __restrict__ deg, const int* __restrict__ adj,
    const float* __restrict__ dinv, const float* __restrict__ bias,
    void* __restrict__ outv, int N, int mode) {
    int grp = threadIdx.x >> 5;
    int l   = threadIdx.x & 31;
    int c4  = l * 4;
    int i = blockIdx.x * NPB + grp;
    if (i >= N) return;
    int r0 = rowptr[i];
    int d  = deg[i];
    float4 a0 = h4f(*(const uint2*)(g + (size_t)i * DH + c4));   // self term
    float4 a1 = make_float4(0.f, 0.f, 0.f, 0.f);
    float4 a2 = make_float4(0.f, 0.f, 0.f, 0.f);
    float4 a3 = make_float4(0.f, 0.f, 0.f, 0.f);
    int r = 0;
    for (; r + 4 <= d; r += 4) {
        int j0 = adj[r0 + r];
        int j1 = adj[r0 + r + 1];
        int j2 = adj[r0 + r + 2];
        int j3 = adj[r0 + r + 3];
        uint2 u0 = *(const uint2*)(g + (size_t)j0 * DH + c4);
        uint2 u1 = *(const uint2*)(g + (size_t)j1 * DH + c4);
        uint2 u2 = *(const uint2*)(g + (size_t)j2 * DH + c4);
        uint2 u3 = *(const uint2*)(g + (size_t)j3 * DH + c4);
        f4acc(a0, h4f(u0)); f4acc(a1, h4f(u1)); f4acc(a2, h4f(u2)); f4acc(a3, h4f(u3));
    }
    for (; r < d; r++) {
        int j = adj[r0 + r];
        f4acc(a0, h4f(*(const uint2*)(g + (size_t)j * DH + c4)));
    }
    f4acc(a0, a1); f4acc(a2, a3); f4acc(a0, a2);
    float dv = dinv[i];
    float4 bv = *(const float4*)(bias + c4);
    float4 s;
    s.x = a0.x * dv + bv.x;
    s.y = a0.y * dv + bv.y;
    s.z = a0.z * dv + bv.z;
    s.w = a0.w * dv + bv.w;
    if (mode & 1) {
        s.x = fmaxf(s.x, 0.f); s.y = fmaxf(s.y, 0.f);
        s.z = fmaxf(s.z, 0.f); s.w = fmaxf(s.w, 0.f);
    }
    if (mode & 2) {
        union { _Float16 h[4]; uint2 u; } p;
        p.h[0] = (_Float16)s.x; p.h[1] = (_Float16)s.y;
        p.h[2] = (_Float16)s.z; p.h[3] = (_Float16)s.w;
        *(uint2*)((_Float16*)outv + (size_t)i * DH + c4) = p.u;
    } else {
        *(float4*)((float*)outv + (size_t)i * DH + c4) = s;
    }
}

// ---------------- Decode: out[e] = dot(z[a], z[b]) over 128 (z fp16) ----------------

__global__ __launch_bounds__(256) void decode_kernel(
    const _Float16* __restrict__ z, const int* __restrict__ ea, const int* __restrict__ eb,
    float* __restrict__ out, int EL) {
    int e = blockIdx.x * 8 + (threadIdx.x >> 5);
    int l = threadIdx.x & 31;
    if (e >= EL) return;
    int a = ea[e], b = eb[e];
    float4 va = h4f(*(const uint2*)(z + (size_t)a * DH + l * 4));
    float4 vb = h4f(*(const uint2*)(z + (size_t)b * DH + l * 4));
    float acc = va.x * vb.x + va.y * vb.y + va.z * vb.z + va.w * vb.w;
#pragma unroll
    for (int off = 16; off > 0; off >>= 1)
        acc += __shfl_down(acc, off, 32);
    if (l == 0) out[e] = acc;
}

// ---------------- Launch ----------------

extern "C" void kernel_launch(void* const* d_in, const int* in_sizes, int n_in,
                              void* d_out, int out_size, void* d_ws, size_t ws_size,
                              hipStream_t stream) {
    const float* x   = (const float*)d_in[0];
    const int*   ei  = (const int*)d_in[1];
    const int*   eli = (const int*)d_in[2];
    const float* W1  = (const float*)d_in[3];
    const float* b1  = (const float*)d_in[4];
    const float* W2  = (const float*)d_in[5];
    const float* b2  = (const float*)d_in[6];
    float* out = (float*)d_out;

    int DHv = in_sizes[4];                 // 128
    int DIN = in_sizes[3] / DHv;           // 256
    int N   = in_sizes[0] / DIN;           // 100000
    int E   = in_sizes[1] / 2;             // 1600000
    int EL  = in_sizes[2] / 2;             // 200000
    const int* src = ei;
    const int* dst = ei + E;
    const int* ea = eli;
    const int* eb = eli + EL;

    int NB = (N + 255) >> BUCKET_BITS;     // 391 buckets

    // workspace carve-up (256B aligned)
    char* ws = (char*)d_ws;
    size_t off = 0;
    auto alloc = [&](size_t bytes) {
        void* p = ws + off;
        off += (bytes + 255) & ~(size_t)255;
        return p;
    };
    int*      cursor = (int*)alloc(512 * 4);
    int*      rowptr = (int*)alloc((size_t)N * 4);
    int*      deg    = (int*)alloc((size_t)N * 4);
    float*    dinv   = (float*)alloc((size_t)N * 4);
    int*      adj    = (int*)alloc((size_t)NB * CAP * 4);   // bucketed, with gaps
    _Float16* WT1    = (_Float16*)alloc((size_t)DIN * DHv * 2);
    _Float16* WT2    = (_Float16*)alloc((size_t)DHv * DHv * 2);
    _Float16* gbuf   = (_Float16*)alloc((size_t)N * DH * 2);   // g1, then g2
    _Float16* hbuf   = (_Float16*)alloc((size_t)N * DH * 2);   // hrelu, then z
    int*      pairs  = (int*)hbuf;   // 8 MB staging; dead before agg1 writes hbuf

    // weight transpose+cast (independent of CSR)
    wcast_kernel<<<DIN / 32, 256, 0, stream>>>(W1, WT1, DIN);
    wcast_kernel<<<DHv / 32, 256, 0, stream>>>(W2, WT2, DHv);

    // CSR build (bucket-partitioned)
    init_cursor_kernel<<<2, 256, 0, stream>>>(cursor);
    int blocksA = (E + EPB - 1) / EPB;
    bucket_scatter_kernel<<<blocksA, 256, 0, stream>>>(src, dst, E, cursor, pairs);
    bucket_build_kernel<<<NB, 256, 0, stream>>>(pairs, cursor, rowptr, deg, dinv, adj, N);

    int gemm_blocks = (N + 127) / 128;
    // conv1: g1 = fp16((x @ W1) * dinv)
    gemm_mfma_kernel<0><<<gemm_blocks, 256, 0, stream>>>(x, WT1, dinv, gbuf, N, DIN);
    // hrelu = fp16(relu(dinv*(g1_self + sum g1[adj]) + b1))
    agg_kernel<<<(N + NPB - 1) / NPB, 256, 0, stream>>>(gbuf, rowptr, deg, adj, dinv, b1, hbuf, N, 3);
    // conv2: g2 = fp16((hrelu @ W2) * dinv)
    gemm_mfma_kernel<1><<<gemm_blocks, 256, 0, stream>>>(hbuf, WT2, dinv, gbuf, N, DHv);
    // z = fp16(dinv*(g2_self + sum g2[adj]) + b2)
    agg_kernel<<<(N + NPB - 1) / NPB, 256, 0, stream>>>(gbuf, rowptr, deg, adj, dinv, b2, hbuf, N, 2);
    // logits (fp32 out)
    decode_kernel<<<(EL + 7) / 8, 256, 0, stream>>>(hbuf, ea, eb, out, EL);
}

// Round 7
// 403.418 us; speedup vs baseline: 2.4847x; 1.0186x over previous
//
#include <hip/hip_runtime.h>
#include <hip/hip_bf16.h>

// GCN link predictor:
//   h = relu(gcnconv(x, W1, b1));  z = gcnconv(h, W2, b2);
//   out[e] = dot(z[eli0[e]], z[eli1[e]])
// g = (x@W)*dinv is produced by the GEMM epilogue so aggregation is a plain gather-sum.
//
// R2: bucket-partitioned CSR build (kills 105 MB partial-line scatter).
// R3: float4 gather + unroll: NEUTRAL (agg is L2-miss byte-rate bound ~3 TB/s).
// R4: g buffers 16-bit: halves gather bytes -> agg ~2x faster (64 us, FETCH 189 MB
//     = 8 XCD x 25.6 MB working set: structural floor for random gather).
// R5: GEMMs -> MFMA f16; all 16-bit tensors fp16.
// R6: GEMM was latency-bound (64 us vs 20 us floor, Occ 21%, VALU 4%): BM 128->64
//     (2x blocks, 2x less per-iter staging) + reg->LDS double buffer, one barrier
//     per K-iter so staging loads overlap MFMA instead of draining at the barrier.

#define DH 128
#define BUCKET_BITS 8
#define CAP 5120            // per-bucket edge capacity; mean 4096 -> 16 sigma slack
#define EPB 4096            // edges per block in stage A
#define KPAD 40             // LDS row stride in halves (80 B; b128 frags 2-way only)

typedef _Float16 half8 __attribute__((ext_vector_type(8)));
typedef float floatx4 __attribute__((ext_vector_type(4)));

// ---------------- CSR build ----------------

__global__ __launch_bounds__(256) void init_cursor_kernel(int* __restrict__ cursor) {
    int i = blockIdx.x * 256 + threadIdx.x;    // 512 total
    cursor[i] = i * CAP;
}

// Stage A: partition edges into buckets by dst>>8; packed = src | (dst&255)<<17
// (valid for N <= 131072; here N = 100000).
__global__ __launch_bounds__(256) void bucket_scatter_kernel(
    const int* __restrict__ src, const int* __restrict__ dst, int E,
    int* __restrict__ cursor, int* __restrict__ pairs) {
    __shared__ int hist[512];
    __shared__ int base[512];
    int t = threadIdx.x;
    int e0 = blockIdx.x * EPB;
    hist[t] = 0; hist[t + 256] = 0;
    __syncthreads();
#pragma unroll
    for (int r = 0; r < EPB / 256; r++) {
        int i = e0 + r * 256 + t;
        if (i < E) atomicAdd(&hist[dst[i] >> BUCKET_BITS], 1);
    }
    __syncthreads();
#pragma unroll
    for (int b = t; b < 512; b += 256) {
        int h = hist[b];
        base[b] = h ? atomicAdd(&cursor[b], h) : 0;
    }
    __syncthreads();
    hist[t] = 0; hist[t + 256] = 0;
    __syncthreads();
#pragma unroll
    for (int r = 0; r < EPB / 256; r++) {
        int i = e0 + r * 256 + t;
        if (i < E) {
            int d = dst[i];
            int b = d >> BUCKET_BITS;
            int rk = atomicAdd(&hist[b], 1);
            pairs[base[b] + rk] = src[i] | ((d & 255) << 17);
        }
    }
}

// Stage B: per-bucket CSR finalize. rowptr/deg/dinv via LDS count+scan,
// adj scatter via LDS cursors into this bucket's private region.
__global__ __launch_bounds__(256) void bucket_build_kernel(
    const int* __restrict__ pairs, const int* __restrict__ cursor,
    int* __restrict__ rowptr, int* __restrict__ deg, float* __restrict__ dinv,
    int* __restrict__ adj, int N) {
    __shared__ int cnt[256];
    __shared__ int sc[256];
    __shared__ int basep[256];
    int b = blockIdx.x;
    int t = threadIdx.x;
    int nb0 = b << BUCKET_BITS;
    int p0 = b * CAP;
    int p1 = cursor[b];               // end of this bucket's pairs
    cnt[t] = 0;
    __syncthreads();
    for (int i = p0 + t; i < p1; i += 256)
        atomicAdd(&cnt[pairs[i] >> 17], 1);
    __syncthreads();
    int c = cnt[t];
    sc[t] = c;
    __syncthreads();
    for (int off = 1; off < 256; off <<= 1) {
        int u = (t >= off) ? sc[t - off] : 0;
        __syncthreads();
        sc[t] += u;
        __syncthreads();
    }
    int ex = sc[t] - c;               // exclusive scan within bucket
    int node = nb0 + t;
    if (node < N) {
        rowptr[node] = p0 + ex;
        deg[node]    = c;
        dinv[node]   = rsqrtf((float)(c + 1));
    }
    basep[t] = p0 + ex;
    cnt[t] = 0;
    __syncthreads();
    for (int i = p0 + t; i < p1; i += 256) {
        int v = pairs[i];
        int li = v >> 17;
        int rk = atomicAdd(&cnt[li], 1);
        adj[basep[li] + rk] = v & 0x1FFFF;
    }
}

// ---------------- Weight transpose+cast: WT[n][k] = fp16(W[k][n]) ----------------
// One 32k x 128n tile per block via LDS.

__global__ __launch_bounds__(256) void wcast_kernel(
    const float* __restrict__ W, _Float16* __restrict__ WT, int K) {
    __shared__ float T[32][132];
    int t = threadIdx.x;
    int k0 = blockIdx.x * 32;
    {
        int kr = t >> 3;              // 0..31
        int c0 = (t & 7) * 16;        // 16 cols per thread
#pragma unroll
        for (int j = 0; j < 4; j++) {
            float4 v = *(const float4*)&W[(size_t)(k0 + kr) * DH + c0 + j * 4];
            T[kr][c0 + j * 4 + 0] = v.x;
            T[kr][c0 + j * 4 + 1] = v.y;
            T[kr][c0 + j * 4 + 2] = v.z;
            T[kr][c0 + j * 4 + 3] = v.w;
        }
    }
    __syncthreads();
    int n  = t >> 1;
    int ko = (t & 1) * 16;
    union { _Float16 h[16]; uint4 u4[2]; } p;
#pragma unroll
    for (int j = 0; j < 16; j++) p.h[j] = (_Float16)T[ko + j][n];
    *(uint4*)&WT[(size_t)n * K + k0 + ko]     = p.u4[0];
    *(uint4*)&WT[(size_t)n * K + k0 + ko + 8] = p.u4[1];
}

// ---------------- MFMA GEMM: out[m][n] = fp16((sum_k A[m][k]*W[k][n]) * dinv[m]) --------
// BM=64, BN=128 (=DH), BK=32. 4 waves; wave w owns m-rows [w*16,w*16+16), all 8 n-tiles.
// Double-buffered: regs load tile k+1 while MFMAing tile k; one barrier per iter.
// mfma_f32_16x16x32_f16(weightfrag, xfrag, acc): operand own-dim = lane&15,
// k = (lane>>4)*8+j; C/D: col(m) = lane&15, row(n) = (lane>>4)*4 + reg.

#define GBM 64

template <int A_FP16>
__global__ __launch_bounds__(256) void gemm_mfma_kernel(
    const void* __restrict__ Ain, const _Float16* __restrict__ WT,
    const float* __restrict__ dinv, _Float16* __restrict__ out,
    int M, int K) {
    __shared__ __attribute__((aligned(16))) _Float16 Alds[2][GBM * KPAD];
    __shared__ __attribute__((aligned(16))) _Float16 Blds[2][128 * KPAD];
    int t = threadIdx.x;
    int w = t >> 6, l = t & 63;
    int r = l & 15, q = l >> 4;
    int m0 = blockIdx.x * GBM;
    // B staging: row n = t>>1 (0..127), 16 halves at ko = (t&1)*16
    int bn  = t >> 1;
    int bko = (t & 1) * 16;
    // A staging: row m = t>>2 (0..63), 8 halves at ko = (t&3)*8
    int am  = t >> 2;
    int ako = (t & 3) * 8;

    floatx4 acc[8];
#pragma unroll
    for (int nt = 0; nt < 8; nt++) acc[nt] = (floatx4)0.f;

    uint4 rb0, rb1;                 // B regs: 32 B
    union { _Float16 h[8]; uint4 u4; } ra;   // A regs (fp16 payload)
    float4 rf0, rf1;                // A regs (fp32 path)

    auto loadB = [&](int k0) {
        const _Float16* bs = WT + (size_t)bn * K + k0 + bko;
        rb0 = *(const uint4*)bs;
        rb1 = *(const uint4*)(bs + 8);
    };
    auto loadA = [&](int k0) {
        int m = m0 + am;
        if (A_FP16) {
            if (m < M) ra.u4 = *(const uint4*)((const _Float16*)Ain + (size_t)m * K + k0 + ako);
            else ra.u4 = make_uint4(0, 0, 0, 0);
        } else {
            if (m < M) {
                const float* as = (const float*)Ain + (size_t)m * K + k0 + ako;
                rf0 = *(const float4*)as;
                rf1 = *(const float4*)(as + 4);
            } else {
                rf0 = make_float4(0.f, 0.f, 0.f, 0.f);
                rf1 = make_float4(0.f, 0.f, 0.f, 0.f);
            }
        }
    };
    auto store = [&](int s) {
        *(uint4*)&Blds[s][bn * KPAD + bko]     = rb0;
        *(uint4*)&Blds[s][bn * KPAD + bko + 8] = rb1;
        if (!A_FP16) {
            ra.h[0] = (_Float16)rf0.x; ra.h[1] = (_Float16)rf0.y;
            ra.h[2] = (_Float16)rf0.z; ra.h[3] = (_Float16)rf0.w;
            ra.h[4] = (_Float16)rf1.x; ra.h[5] = (_Float16)rf1.y;
            ra.h[6] = (_Float16)rf1.z; ra.h[7] = (_Float16)rf1.w;
        }
        *(uint4*)&Alds[s][am * KPAD + ako] = ra.u4;
    };

    loadB(0); loadA(0);
    store(0);
    __syncthreads();
    int cur = 0;
    for (int k0 = 0; k0 < K; k0 += 32) {
        bool has_next = (k0 + 32) < K;
        if (has_next) { loadB(k0 + 32); loadA(k0 + 32); }
        half8 afr = *(const half8*)&Alds[cur][(w * 16 + r) * KPAD + q * 8];
#pragma unroll
        for (int nt = 0; nt < 8; nt++) {
            half8 bfr = *(const half8*)&Blds[cur][(nt * 16 + r) * KPAD + q * 8];
            acc[nt] = __builtin_amdgcn_mfma_f32_16x16x32_f16(bfr, afr, acc[nt], 0, 0, 0);
        }
        if (has_next) { cur ^= 1; store(cur); }
        __syncthreads();
    }

    // epilogue: lane holds m = m0 + w*16 + r; n = nt*16 + q*4 + reg
    int m = m0 + w * 16 + r;
    if (m < M) {
        float dv = dinv[m];
#pragma unroll
        for (int nt = 0; nt < 8; nt++) {
            union { _Float16 h[4]; uint2 u; } p;
#pragma unroll
            for (int reg = 0; reg < 4; reg++)
                p.h[reg] = (_Float16)(acc[nt][reg] * dv);
            *(uint2*)&out[(size_t)m * DH + nt * 16 + q * 4] = p.u;
        }
    }
}

// ---------------- Aggregation ----------------
// out[i] = dinv[i]*(g[i] + sum_j g[adj]) + b. g fp16 (256 B/row).
// 32-lane group per node, uint2 (4 halves)/lane; 4-edge unroll, 4 fp32 acc chains.
// mode bit0: relu, bit1: write fp16 (else fp32).

#define NPB 8    // nodes (32-lane groups) per 256-thread block

__device__ __forceinline__ float4 h4f(uint2 uu) {
    union { uint2 u; _Float16 h[4]; } c; c.u = uu;
    return make_float4((float)c.h[0], (float)c.h[1], (float)c.h[2], (float)c.h[3]);
}

__device__ __forceinline__ void f4acc(float4& a, const float4 v) {
    a.x += v.x; a.y += v.y; a.z += v.z; a.w += v.w;
}

__global__ __launch_bounds__(256) void agg_kernel(
    const _Float16* __restrict__ g, const int* __restrict__ rowptr,
    const int* __restrict__ deg, const int* __restrict__ adj,
    const float* __restrict__ dinv, const float* __restrict__ bias,
    void* __restrict__ outv, int N, int mode) {
    int grp = threadIdx.x >> 5;
    int l   = threadIdx.x & 31;
    int c4  = l * 4;
    int i = blockIdx.x * NPB + grp;
    if (i >= N) return;
    int r0 = rowptr[i];
    int d  = deg[i];
    float4 a0 = h4f(*(const uint2*)(g + (size_t)i * DH + c4));   // self term
    float4 a1 = make_float4(0.f, 0.f, 0.f, 0.f);
    float4 a2 = make_float4(0.f, 0.f, 0.f, 0.f);
    float4 a3 = make_float4(0.f, 0.f, 0.f, 0.f);
    int r = 0;
    for (; r + 4 <= d; r += 4) {
        int j0 = adj[r0 + r];
        int j1 = adj[r0 + r + 1];
        int j2 = adj[r0 + r + 2];
        int j3 = adj[r0 + r + 3];
        uint2 u0 = *(const uint2*)(g + (size_t)j0 * DH + c4);
        uint2 u1 = *(const uint2*)(g + (size_t)j1 * DH + c4);
        uint2 u2 = *(const uint2*)(g + (size_t)j2 * DH + c4);
        uint2 u3 = *(const uint2*)(g + (size_t)j3 * DH + c4);
        f4acc(a0, h4f(u0)); f4acc(a1, h4f(u1)); f4acc(a2, h4f(u2)); f4acc(a3, h4f(u3));
    }
    for (; r < d; r++) {
        int j = adj[r0 + r];
        f4acc(a0, h4f(*(const uint2*)(g + (size_t)j * DH + c4)));
    }
    f4acc(a0, a1); f4acc(a2, a3); f4acc(a0, a2);
    float dv = dinv[i];
    float4 bv = *(const float4*)(bias + c4);
    float4 s;
    s.x = a0.x * dv + bv.x;
    s.y = a0.y * dv + bv.y;
    s.z = a0.z * dv + bv.z;
    s.w = a0.w * dv + bv.w;
    if (mode & 1) {
        s.x = fmaxf(s.x, 0.f); s.y = fmaxf(s.y, 0.f);
        s.z = fmaxf(s.z, 0.f); s.w = fmaxf(s.w, 0.f);
    }
    if (mode & 2) {
        union { _Float16 h[4]; uint2 u; } p;
        p.h[0] = (_Float16)s.x; p.h[1] = (_Float16)s.y;
        p.h[2] = (_Float16)s.z; p.h[3] = (_Float16)s.w;
        *(uint2*)((_Float16*)outv + (size_t)i * DH + c4) = p.u;
    } else {
        *(float4*)((float*)outv + (size_t)i * DH + c4) = s;
    }
}

// ---------------- Decode: out[e] = dot(z[a], z[b]) over 128 (z fp16) ----------------

__global__ __launch_bounds__(256) void decode_kernel(
    const _Float16* __restrict__ z, const int* __restrict__ ea, const int* __restrict__ eb,
    float* __restrict__ out, int EL) {
    int e = blockIdx.x * 8 + (threadIdx.x >> 5);
    int l = threadIdx.x & 31;
    if (e >= EL) return;
    int a = ea[e], b = eb[e];
    float4 va = h4f(*(const uint2*)(z + (size_t)a * DH + l * 4));
    float4 vb = h4f(*(const uint2*)(z + (size_t)b * DH + l * 4));
    float acc = va.x * vb.x + va.y * vb.y + va.z * vb.z + va.w * vb.w;
#pragma unroll
    for (int off = 16; off > 0; off >>= 1)
        acc += __shfl_down(acc, off, 32);
    if (l == 0) out[e] = acc;
}

// ---------------- Launch ----------------

extern "C" void kernel_launch(void* const* d_in, const int* in_sizes, int n_in,
                              void* d_out, int out_size, void* d_ws, size_t ws_size,
                              hipStream_t stream) {
    const float* x   = (const float*)d_in[0];
    const int*   ei  = (const int*)d_in[1];
    const int*   eli = (const int*)d_in[2];
    const float* W1  = (const float*)d_in[3];
    const float* b1  = (const float*)d_in[4];
    const float* W2  = (const float*)d_in[5];
    const float* b2  = (const float*)d_in[6];
    float* out = (float*)d_out;

    int DHv = in_sizes[4];                 // 128
    int DIN = in_sizes[3] / DHv;           // 256
    int N   = in_sizes[0] / DIN;           // 100000
    int E   = in_sizes[1] / 2;             // 1600000
    int EL  = in_sizes[2] / 2;             // 200000
    const int* src = ei;
    const int* dst = ei + E;
    const int* ea = eli;
    const int* eb = eli + EL;

    int NB = (N + 255) >> BUCKET_BITS;     // 391 buckets

    // workspace carve-up (256B aligned)
    char* ws = (char*)d_ws;
    size_t off = 0;
    auto alloc = [&](size_t bytes) {
        void* p = ws + off;
        off += (bytes + 255) & ~(size_t)255;
        return p;
    };
    int*      cursor = (int*)alloc(512 * 4);
    int*      rowptr = (int*)alloc((size_t)N * 4);
    int*      deg    = (int*)alloc((size_t)N * 4);
    float*    dinv   = (float*)alloc((size_t)N * 4);
    int*      adj    = (int*)alloc((size_t)NB * CAP * 4);   // bucketed, with gaps
    _Float16* WT1    = (_Float16*)alloc((size_t)DIN * DHv * 2);
    _Float16* WT2    = (_Float16*)alloc((size_t)DHv * DHv * 2);
    _Float16* gbuf   = (_Float16*)alloc((size_t)N * DH * 2);   // g1, then g2
    _Float16* hbuf   = (_Float16*)alloc((size_t)N * DH * 2);   // hrelu, then z
    int*      pairs  = (int*)hbuf;   // 8 MB staging; dead before agg1 writes hbuf

    // weight transpose+cast (independent of CSR)
    wcast_kernel<<<DIN / 32, 256, 0, stream>>>(W1, WT1, DIN);
    wcast_kernel<<<DHv / 32, 256, 0, stream>>>(W2, WT2, DHv);

    // CSR build (bucket-partitioned)
    init_cursor_kernel<<<2, 256, 0, stream>>>(cursor);
    int blocksA = (E + EPB - 1) / EPB;
    bucket_scatter_kernel<<<blocksA, 256, 0, stream>>>(src, dst, E, cursor, pairs);
    bucket_build_kernel<<<NB, 256, 0, stream>>>(pairs, cursor, rowptr, deg, dinv, adj, N);

    int gemm_blocks = (N + GBM - 1) / GBM;
    // conv1: g1 = fp16((x @ W1) * dinv)
    gemm_mfma_kernel<0><<<gemm_blocks, 256, 0, stream>>>(x, WT1, dinv, gbuf, N, DIN);
    // hrelu = fp16(relu(dinv*(g1_self + sum g1[adj]) + b1))
    agg_kernel<<<(N + NPB - 1) / NPB, 256, 0, stream>>>(gbuf, rowptr, deg, adj, dinv, b1, hbuf, N, 3);
    // conv2: g2 = fp16((hrelu @ W2) * dinv)
    gemm_mfma_kernel<1><<<gemm_blocks, 256, 0, stream>>>(hbuf, WT2, dinv, gbuf, N, DHv);
    // z = fp16(dinv*(g2_self + sum g2[adj]) + b2)
    agg_kernel<<<(N + NPB - 1) / NPB, 256, 0, stream>>>(gbuf, rowptr, deg, adj, dinv, b2, hbuf, N, 2);
    // logits (fp32 out)
    decode_kernel<<<(EL + 7) / 8, 256, 0, stream>>>(hbuf, ea, eb, out, EL);
}